// Round 5
// baseline (3729.296 us; speedup 1.0000x reference)
//
#include <hip/hip_runtime.h>

#define D 64
#define SCAN_B 1024

__device__ __forceinline__ float sigmoidf_(float x) {
    return 1.0f / (1.0f + __expf(-x));
}
__device__ __forceinline__ float h2f(ushort u) {
    _Float16 h;
    __builtin_memcpy(&h, &u, 2);
    return (float)h;
}
__device__ __forceinline__ ushort f2h(float f) {
    _Float16 h = (_Float16)f;  // v_cvt_f16_f32, RNE
    ushort u;
    __builtin_memcpy(&u, &h, 2);
    return u;
}
__device__ __forceinline__ float2 up2(uint v) {
    float2 r;
    r.x = h2f((ushort)(v & 0xffffu));
    r.y = h2f((ushort)(v >> 16));
    return r;
}

// ---------------- precompute kernels ----------------

__global__ __launch_bounds__(256) void count_deg(const int* __restrict__ dst,
                                                 int* __restrict__ cnt, int E) {
    int e = blockIdx.x * 256 + threadIdx.x;
    if (e < E) atomicAdd(&cnt[dst[e]], 1);
}

__global__ __launch_bounds__(256) void calc_dinv(const int* __restrict__ cnt,
                                                 float* __restrict__ dinv,
                                                 float* __restrict__ rdinv, int N) {
    int n = blockIdx.x * 256 + threadIdx.x;
    if (n < N) {
        float c = (float)cnt[n] + 1.0f;
        dinv[n] = rsqrtf(c);
        rdinv[n] = sqrtf(c);
    }
}

__global__ __launch_bounds__(SCAN_B) void scan_block(const int* __restrict__ cnt,
                                                     int* __restrict__ out,
                                                     int* __restrict__ bsum, int N) {
    __shared__ int tmp[SCAN_B];
    int t = threadIdx.x;
    int gbase = blockIdx.x * SCAN_B;
    int v = (gbase + t < N) ? cnt[gbase + t] : 0;
    tmp[t] = v;
    __syncthreads();
    for (int off = 1; off < SCAN_B; off <<= 1) {
        int x = (t >= off) ? tmp[t - off] : 0;
        __syncthreads();
        tmp[t] += x;
        __syncthreads();
    }
    int incl = tmp[t];
    if (gbase + t < N) out[gbase + t] = incl - v;  // exclusive
    if (t == SCAN_B - 1) bsum[blockIdx.x] = incl;
}

__global__ __launch_bounds__(256) void scan_add(int* __restrict__ ptr,
                                                const int* __restrict__ boff,
                                                int* __restrict__ cursor, int N, int E) {
    int i = blockIdx.x * 256 + threadIdx.x;
    if (i < N) {
        int v = ptr[i] + boff[i / SCAN_B];
        ptr[i] = v;
        cursor[i] = v;
    }
    if (i == 0) ptr[N] = E;
}

__global__ __launch_bounds__(256) void fill_csr(const int* __restrict__ src,
                                                const int* __restrict__ dst,
                                                int* __restrict__ cursor,
                                                int* __restrict__ sorted, int E) {
    int e = blockIdx.x * 256 + threadIdx.x;
    if (e < E) {
        int p = atomicAdd(&cursor[dst[e]], 1);
        sorted[p] = src[e];
    }
}

// q[n] = Agg(1)[n] = dinv[n]*(sum_nbr dinv[src] + dinv[n])
__global__ __launch_bounds__(256) void qsum_k(const int* __restrict__ ptr,
                                              const int* __restrict__ srcs,
                                              const float* __restrict__ dinv,
                                              float* __restrict__ q, int N) {
    int n = blockIdx.x * 256 + threadIdx.x;
    if (n >= N) return;
    float s = dinv[n];
    int b = ptr[n], e = ptr[n + 1];
    for (int i = b; i < e; i++) s += dinv[srcs[i]];
    q[n] = dinv[n] * s;
}

// actd0 = fp16(x * dinv[n])
__global__ __launch_bounds__(256) void prep_xd(const float* __restrict__ x,
                                               const float* __restrict__ dinv,
                                               ushort* __restrict__ actd, int N16) {
    int p = blockIdx.x * 256 + threadIdx.x;
    if (p >= N16) return;
    int n = p >> 4;
    float d = dinv[n];
    float4 v = reinterpret_cast<const float4*>(x)[p];
    ushort4 o;
    o.x = f2h(v.x * d);
    o.y = f2h(v.y * d);
    o.z = f2h(v.z * d);
    o.w = f2h(v.w * d);
    reinterpret_cast<ushort4*>(actd)[p] = o;
}

// ---------------- per-layer kernels ----------------

// 2 nodes per wave (half = lane>>5), ushort2 per lane (features 2l, 2l+1).
// z[n] = dinv[n] * (actd[n] + sum_{src} actd[src]); optional BN stats of actd*rdinv.
__global__ __launch_bounds__(256) void agg_gather2(const ushort* __restrict__ actd,
                                                   const int* __restrict__ ptr,
                                                   const int* __restrict__ srcs,
                                                   const float* __restrict__ dinv,
                                                   const float* __restrict__ rdinv,
                                                   float* __restrict__ z,
                                                   float* __restrict__ ssum,
                                                   float* __restrict__ sssq,
                                                   int N, int E) {
    __shared__ float red[2][4][64];
    int lane = threadIdx.x & 63;
    int wv = threadIdx.x >> 6;
    int l = lane & 31;
    int half = lane >> 5;
    int Np = (N + 1) >> 1;
    int Em1 = E - 1;
    const bool do_stats = (ssum != nullptr);
    float2 ps = make_float2(0.f, 0.f), pq = make_float2(0.f, 0.f);
    for (int p = blockIdx.x * 4 + wv; p < Np; p += gridDim.x * 4) {
        int n = 2 * p + half;
        bool valid = n < N;
        int s = 0, d = 0;
        if (valid) {
            s = ptr[n];
            d = ptr[n + 1] - s;
        }
        uint self = valid
            ? *reinterpret_cast<const uint*>(actd + ((size_t)n << 6) + (l << 1))
            : 0u;
        float2 acc = up2(self);
        if (do_stats && valid) {
            float r = rdinv[n];
            float ax = acc.x * r, ay = acc.y * r;
            ps.x += ax; ps.y += ay;
            pq.x += ax * ax; pq.y += ay * ay;
        }
        int d0 = __shfl(d, 0);
        int d1 = __shfl(d, 32);
        int dmax = max(d0, d1);
#define GSTEP(j)                                                                    \
        {                                                                           \
            int ii = it + (j);                                                      \
            int idx = min(s + ii, Em1);                                             \
            int uu = srcs[idx];                                                     \
            uint vv = *reinterpret_cast<const uint*>(actd + ((size_t)uu << 6) +     \
                                                     (l << 1));                     \
            float w = (ii < d) ? 1.0f : 0.0f;                                       \
            float2 f = up2(vv);                                                     \
            acc.x = fmaf(w, f.x, acc.x);                                            \
            acc.y = fmaf(w, f.y, acc.y);                                            \
        }
        for (int it = 0; it < dmax; it += 8) {
            GSTEP(0) GSTEP(1) GSTEP(2) GSTEP(3)
            GSTEP(4) GSTEP(5) GSTEP(6) GSTEP(7)
        }
#undef GSTEP
        if (valid) {
            float dn = dinv[n];
            float2 o;
            o.x = acc.x * dn;
            o.y = acc.y * dn;
            *reinterpret_cast<float2*>(z + ((size_t)n << 6) + (l << 1)) = o;
        }
    }
    if (do_stats) {
        // fold half1 into half0, then per-wave partials into LDS
        ps.x += __shfl_xor(ps.x, 32);
        ps.y += __shfl_xor(ps.y, 32);
        pq.x += __shfl_xor(pq.x, 32);
        pq.y += __shfl_xor(pq.y, 32);
        if (half == 0) {
            red[0][wv][2 * l + 0] = ps.x;
            red[0][wv][2 * l + 1] = ps.y;
            red[1][wv][2 * l + 0] = pq.x;
            red[1][wv][2 * l + 1] = pq.y;
        }
        __syncthreads();
        if (wv == 0) {
            float t0 = red[0][0][lane] + red[0][1][lane] + red[0][2][lane] + red[0][3][lane];
            float t1 = red[1][0][lane] + red[1][1][lane] + red[1][2][lane] + red[1][3][lane];
            atomicAdd(&ssum[lane], t0);
            atomicAdd(&sssq[lane], t1);
        }
    }
}

// LDS-staged GEMM: block = 64-node tile, lane = output column j.
// pre[n][j] = sum_k z[n][k]*A[k]*W[k][j] + q[n]*u[j] + b[j]; act = MODE(pre)
// OUT_HALF: write fp16(act*dinv); else raw f32 act + fused BN stats.
template <int MODE, bool HAS_AFF, bool OUT_HALF>
__global__ __launch_bounds__(256, 4) void gemm_lds(const float* __restrict__ z,
                                                   const float* __restrict__ W,
                                                   const float* __restrict__ Aaf,
                                                   const float* __restrict__ u,
                                                   const float* __restrict__ bias,
                                                   const float* __restrict__ q,
                                                   const float* __restrict__ dinv,
                                                   ushort* __restrict__ outh,
                                                   float* __restrict__ outf,
                                                   float* __restrict__ ssum,
                                                   float* __restrict__ sssq, int N) {
    __shared__ float zs[64 * 64];
    __shared__ float qs[64];
    __shared__ float dvs[64];
    __shared__ float sred[2][4][64];
    int tid = threadIdx.x;
    int lane = tid & 63;
    int wv = tid >> 6;
    int tb = blockIdx.x * 64;

    // stage z tile (coalesced float4), zero-pad tail
    {
        const float4* zg = reinterpret_cast<const float4*>(z);
        float4* zs4 = reinterpret_cast<float4*>(zs);
#pragma unroll
        for (int f = 0; f < 4; f++) {
            int fl = tid + f * 256;
            int node = tb + (fl >> 4);
            float4 v = make_float4(0.f, 0.f, 0.f, 0.f);
            if (node < N) v = zg[(size_t)tb * 16 + fl];
            zs4[fl] = v;
        }
        if (tid < 64) {
            int node = tb + tid;
            qs[tid] = (node < N) ? q[node] : 0.f;
            dvs[tid] = (node < N) ? dinv[node] : 0.f;
        }
    }

    // per-lane W column into registers (coalesced per wave), fold Aaf
    float Wreg[64];
#pragma unroll
    for (int k = 0; k < 64; k++) {
        float w = W[k * 64 + lane];
        if (HAS_AFF) w *= Aaf[k];
        Wreg[k] = w;
    }
    float b_l = bias[lane];
    float u_l = 0.f;
    if (HAS_AFF) u_l = u[lane];

    __syncthreads();

    float sa = 0.f, sb = 0.f;
    const float4* zrow = reinterpret_cast<const float4*>(zs);
#pragma unroll
    for (int g = 0; g < 4; g++) {
        int r0 = wv * 16 + g * 4;
        float acc0, acc1, acc2, acc3;
        if (HAS_AFF) {
            acc0 = fmaf(qs[r0 + 0], u_l, b_l);
            acc1 = fmaf(qs[r0 + 1], u_l, b_l);
            acc2 = fmaf(qs[r0 + 2], u_l, b_l);
            acc3 = fmaf(qs[r0 + 3], u_l, b_l);
        } else {
            acc0 = acc1 = acc2 = acc3 = b_l;
        }
#pragma unroll
        for (int k4 = 0; k4 < 16; k4++) {
            float4 a0 = zrow[(r0 + 0) * 16 + k4];
            float4 a1 = zrow[(r0 + 1) * 16 + k4];
            float4 a2 = zrow[(r0 + 2) * 16 + k4];
            float4 a3 = zrow[(r0 + 3) * 16 + k4];
            acc0 = fmaf(a0.x, Wreg[4 * k4 + 0], acc0);
            acc1 = fmaf(a1.x, Wreg[4 * k4 + 0], acc1);
            acc2 = fmaf(a2.x, Wreg[4 * k4 + 0], acc2);
            acc3 = fmaf(a3.x, Wreg[4 * k4 + 0], acc3);
            acc0 = fmaf(a0.y, Wreg[4 * k4 + 1], acc0);
            acc1 = fmaf(a1.y, Wreg[4 * k4 + 1], acc1);
            acc2 = fmaf(a2.y, Wreg[4 * k4 + 1], acc2);
            acc3 = fmaf(a3.y, Wreg[4 * k4 + 1], acc3);
            acc0 = fmaf(a0.z, Wreg[4 * k4 + 2], acc0);
            acc1 = fmaf(a1.z, Wreg[4 * k4 + 2], acc1);
            acc2 = fmaf(a2.z, Wreg[4 * k4 + 2], acc2);
            acc3 = fmaf(a3.z, Wreg[4 * k4 + 2], acc3);
            acc0 = fmaf(a0.w, Wreg[4 * k4 + 3], acc0);
            acc1 = fmaf(a1.w, Wreg[4 * k4 + 3], acc1);
            acc2 = fmaf(a2.w, Wreg[4 * k4 + 3], acc2);
            acc3 = fmaf(a3.w, Wreg[4 * k4 + 3], acc3);
        }
        float accs[4] = {acc0, acc1, acc2, acc3};
#pragma unroll
        for (int i = 0; i < 4; i++) {
            float o = accs[i];
            float a = (MODE == 0) ? sigmoidf_(o)
                                  : ((MODE == 1) ? o : sigmoidf_(0.5f * o));
            int gn = tb + r0 + i;
            if (gn < N) {
                if (OUT_HALF) {
                    outh[(size_t)gn * 64 + lane] = f2h(a * dvs[r0 + i]);
                } else {
                    outf[(size_t)gn * 64 + lane] = a;
                    sa += a;
                    sb += a * a;
                }
            }
        }
    }
    if (!OUT_HALF) {
        sred[0][wv][lane] = sa;
        sred[1][wv][lane] = sb;
        __syncthreads();
        if (wv == 0) {
            float t0 = sred[0][0][lane] + sred[0][1][lane] + sred[0][2][lane] + sred[0][3][lane];
            float t1 = sred[1][0][lane] + sred[1][1][lane] + sred[1][2][lane] + sred[1][3][lane];
            atomicAdd(&ssum[lane], t0);
            atomicAdd(&sssq[lane], t1);
        }
    }
}

// A[c] = rsqrt(var+eps)*gamma[c];  C[c] = beta[c] - mean*A[c]
__global__ __launch_bounds__(64) void finalize_aff(const float* __restrict__ ssum,
                                                   const float* __restrict__ sssq,
                                                   const float* __restrict__ gamma,
                                                   const float* __restrict__ beta,
                                                   float* __restrict__ A,
                                                   float* __restrict__ C, float invN) {
    int c = threadIdx.x;
    float m = ssum[c] * invN;
    float var = sssq[c] * invN - m * m;
    float rs = rsqrtf(var + 1e-4f);
    float a = rs * gamma[c];
    A[c] = a;
    C[c] = fmaf(-m, a, beta[c]);
}

// u[j] = sum_k C[k]*W[k][j]
__global__ __launch_bounds__(64) void compute_u(const float* __restrict__ C,
                                                const float* __restrict__ W,
                                                float* __restrict__ u) {
    int j = threadIdx.x;
    float s = 0.f;
    for (int k = 0; k < 64; k++) s = fmaf(C[k], W[k * 64 + j], s);
    u[j] = s;
}

__global__ __launch_bounds__(256) void bn_apply_h(const ushort* __restrict__ actd,
                                                  const float* __restrict__ rdinv,
                                                  const float* __restrict__ A,
                                                  const float* __restrict__ C,
                                                  float* __restrict__ out, int N16) {
    int p = blockIdx.x * 256 + threadIdx.x;
    if (p >= N16) return;
    int n = p >> 4;
    int cb = (p & 15) * 4;
    float r = rdinv[n];
    ushort4 v = reinterpret_cast<const ushort4*>(actd)[p];
    float4 o;
    o.x = fmaf(h2f(v.x) * r, A[cb + 0], C[cb + 0]);
    o.y = fmaf(h2f(v.y) * r, A[cb + 1], C[cb + 1]);
    o.z = fmaf(h2f(v.z) * r, A[cb + 2], C[cb + 2]);
    o.w = fmaf(h2f(v.w) * r, A[cb + 3], C[cb + 3]);
    reinterpret_cast<float4*>(out)[p] = o;
}

__global__ __launch_bounds__(256) void bn_apply_f32(const float* __restrict__ act,
                                                    const float* __restrict__ A,
                                                    const float* __restrict__ C,
                                                    float* __restrict__ out, int N16) {
    int p = blockIdx.x * 256 + threadIdx.x;
    if (p >= N16) return;
    int cb = (p & 15) * 4;
    float4 v = reinterpret_cast<const float4*>(act)[p];
    float4 o;
    o.x = fmaf(v.x, A[cb + 0], C[cb + 0]);
    o.y = fmaf(v.y, A[cb + 1], C[cb + 1]);
    o.z = fmaf(v.z, A[cb + 2], C[cb + 2]);
    o.w = fmaf(v.w, A[cb + 3], C[cb + 3]);
    reinterpret_cast<float4*>(out)[p] = o;
}

// ---------------- launch ----------------

extern "C" void kernel_launch(void* const* d_in, const int* in_sizes, int n_in,
                              void* d_out, int out_size, void* d_ws, size_t ws_size,
                              hipStream_t stream) {
    const int N = in_sizes[0] / D;
    const int E = in_sizes[1] / 2;

    const float* x = (const float*)d_in[0];
    const int* ei = (const int*)d_in[1];
    const int* src_in = ei;
    const int* dst_in = ei + E;
    const float* encW = (const float*)d_in[3];
    const float* encb = (const float*)d_in[4];
    const float* encg = (const float*)d_in[5];
    const float* encbe = (const float*)d_in[6];
    const float* attW = (const float*)d_in[7];
    const float* attb = (const float*)d_in[8];
    const float* attg = (const float*)d_in[9];
    const float* attbe = (const float*)d_in[10];
    const float* strW = (const float*)d_in[11];
    const float* strb = (const float*)d_in[12];
    const float* strg = (const float*)d_in[13];
    const float* strbe = (const float*)d_in[14];

    char* ws = (char*)d_ws;
    size_t off = 0;
    auto alloc = [&](size_t bytes) -> char* {
        char* p = ws + off;
        off += (bytes + 255) & ~(size_t)255;
        return p;
    };
    int* cnt = (int*)alloc((size_t)N * 4);
    int* csr = (int*)alloc((size_t)(N + 1) * 4);
    int* cursor = (int*)alloc((size_t)N * 4);
    int* sorted = (int*)alloc((size_t)E * 4);
    int* bsum = (int*)alloc(1024 * 4);
    int* boff = (int*)alloc(1024 * 4);
    int* dummy = (int*)alloc(1024 * 4);
    float* dinv = (float*)alloc((size_t)N * 4);
    float* rdinv = (float*)alloc((size_t)N * 4);
    float* q = (float*)alloc((size_t)N * 4);
    float* stats = (float*)alloc(6 * 128 * 4);
    float* aff = (float*)alloc(6 * 128 * 4);
    float* ubuf = (float*)alloc(6 * 64 * 4);
    float* z = (float*)alloc((size_t)N * D * 4);
    float* fbuf = (float*)alloc((size_t)N * D * 4);
    ushort* hA = (ushort*)alloc((size_t)N * D * 2);
    ushort* hB = (ushort*)alloc((size_t)N * D * 2);

    float* out_str = (float*)d_out;
    float* out_att = out_str + (size_t)N * D;
    float* out_enc = out_att + (size_t)N * D;

    hipMemsetAsync(cnt, 0, (size_t)N * 4, stream);
    hipMemsetAsync(stats, 0, 6 * 128 * 4, stream);

    int gE = (E + 255) / 256;
    int gN = (N + 255) / 256;
    int gT = (N + 63) / 64;  // gemm tiles
    int nsb = (N + SCAN_B - 1) / SCAN_B;
    int N16 = N * 16;
    int g16 = (N16 + 255) / 256;
    float invN = 1.0f / (float)N;

    // ---- CSR build + norm precompute ----
    count_deg<<<gE, 256, 0, stream>>>(dst_in, cnt, E);
    calc_dinv<<<gN, 256, 0, stream>>>(cnt, dinv, rdinv, N);
    scan_block<<<nsb, SCAN_B, 0, stream>>>(cnt, csr, bsum, N);
    scan_block<<<1, SCAN_B, 0, stream>>>(bsum, boff, dummy, nsb);
    scan_add<<<gN, 256, 0, stream>>>(csr, boff, cursor, N, E);
    fill_csr<<<gE, 256, 0, stream>>>(src_in, dst_in, cursor, sorted, E);
    qsum_k<<<gN, 256, 0, stream>>>(csr, sorted, dinv, q, N);

    float* A0 = aff + 0 * 128; float* C0 = A0 + 64;
    float* A1 = aff + 1 * 128; float* C1 = A1 + 64;
    float* A2 = aff + 2 * 128; float* C2 = A2 + 64;
    float* A3 = aff + 3 * 128; float* C3 = A3 + 64;
    float* A4 = aff + 4 * 128; float* C4 = A4 + 64;
    float* A5 = aff + 5 * 128; float* C5 = A5 + 64;

    // ---- encoder layer 1 ----
    prep_xd<<<g16, 256, 0, stream>>>(x, dinv, hA, N16);
    agg_gather2<<<2048, 256, 0, stream>>>(hA, csr, sorted, dinv, rdinv, z,
                                          nullptr, nullptr, N, E);
    gemm_lds<0, false, true><<<gT, 256, 0, stream>>>(z, encW, nullptr, nullptr,
                                                     encb, q, dinv, hB, nullptr,
                                                     nullptr, nullptr, N);
    // ---- encoder layer 2 ----
    agg_gather2<<<2048, 256, 0, stream>>>(hB, csr, sorted, dinv, rdinv, z,
                                          stats + 0, stats + 64, N, E);
    finalize_aff<<<1, 64, 0, stream>>>(stats + 0, stats + 64, encg, encbe, A0, C0, invN);
    compute_u<<<1, 64, 0, stream>>>(C0, encW + 4096, ubuf + 0);
    gemm_lds<0, true, true><<<gT, 256, 0, stream>>>(z, encW + 4096, A0, ubuf + 0,
                                                    encb + 64, q, dinv, hA, nullptr,
                                                    nullptr, nullptr, N);
    // ---- z2 = Agg(x_enc-act), shared by att1 & str1; also enc2 stats ----
    agg_gather2<<<2048, 256, 0, stream>>>(hA, csr, sorted, dinv, rdinv, z,
                                          stats + 128, stats + 192, N, E);
    finalize_aff<<<1, 64, 0, stream>>>(stats + 128, stats + 192, encg + 64,
                                       encbe + 64, A1, C1, invN);
    compute_u<<<1, 64, 0, stream>>>(C1, attW, ubuf + 64);
    compute_u<<<1, 64, 0, stream>>>(C1, strW, ubuf + 128);
    bn_apply_h<<<g16, 256, 0, stream>>>(hA, rdinv, A1, C1, out_enc, N16);
    gemm_lds<0, true, true><<<gT, 256, 0, stream>>>(z, attW, A1, ubuf + 64, attb,
                                                    q, dinv, hB, nullptr,
                                                    nullptr, nullptr, N);
    gemm_lds<0, true, true><<<gT, 256, 0, stream>>>(z, strW, A1, ubuf + 128, strb,
                                                    q, dinv, hA, nullptr,
                                                    nullptr, nullptr, N);
    // ---- attribute layer 2 (terminal, linear; BN stats fused) ----
    agg_gather2<<<2048, 256, 0, stream>>>(hB, csr, sorted, dinv, rdinv, z,
                                          stats + 256, stats + 320, N, E);
    finalize_aff<<<1, 64, 0, stream>>>(stats + 256, stats + 320, attg, attbe,
                                       A2, C2, invN);
    compute_u<<<1, 64, 0, stream>>>(C2, attW + 4096, ubuf + 192);
    gemm_lds<1, true, false><<<gT, 256, 0, stream>>>(z, attW + 4096, A2, ubuf + 192,
                                                     attb + 64, q, dinv, nullptr,
                                                     fbuf, stats + 384, stats + 448, N);
    finalize_aff<<<1, 64, 0, stream>>>(stats + 384, stats + 448, attg + 64,
                                       attbe + 64, A3, C3, invN);
    bn_apply_f32<<<g16, 256, 0, stream>>>(fbuf, A3, C3, out_att, N16);
    // ---- structure layer 2 (terminal, sigmoid(0.5x); BN stats fused) ----
    agg_gather2<<<2048, 256, 0, stream>>>(hA, csr, sorted, dinv, rdinv, z,
                                          stats + 512, stats + 576, N, E);
    finalize_aff<<<1, 64, 0, stream>>>(stats + 512, stats + 576, strg, strbe,
                                       A4, C4, invN);
    compute_u<<<1, 64, 0, stream>>>(C4, strW + 4096, ubuf + 320);
    gemm_lds<2, true, false><<<gT, 256, 0, stream>>>(z, strW + 4096, A4, ubuf + 320,
                                                     strb + 64, q, dinv, nullptr,
                                                     fbuf, stats + 640, stats + 704, N);
    finalize_aff<<<1, 64, 0, stream>>>(stats + 640, stats + 704, strg + 64,
                                       strbe + 64, A5, C5, invN);
    bn_apply_f32<<<g16, 256, 0, stream>>>(fbuf, A5, C5, out_str, N16);
}

// Round 6
// 767.709 us; speedup vs baseline: 4.8577x; 4.8577x over previous
//
#include <hip/hip_runtime.h>

#define D 64
#define SCAN_B 1024

typedef __attribute__((ext_vector_type(8))) _Float16 f16x8;
typedef __attribute__((ext_vector_type(4))) float f32x4;

__device__ __forceinline__ float sigmoidf_(float x) {
    return 1.0f / (1.0f + __expf(-x));
}
__device__ __forceinline__ float h2f(ushort u) {
    _Float16 h;
    __builtin_memcpy(&h, &u, 2);
    return (float)h;
}
__device__ __forceinline__ ushort f2h(float f) {
    _Float16 h = (_Float16)f;  // v_cvt_f16_f32, RNE
    ushort u;
    __builtin_memcpy(&u, &h, 2);
    return u;
}
__device__ __forceinline__ float2 up2(uint v) {
    float2 r;
    r.x = h2f((ushort)(v & 0xffffu));
    r.y = h2f((ushort)(v >> 16));
    return r;
}

// ---------------- precompute kernels ----------------

__global__ __launch_bounds__(256) void count_deg(const int* __restrict__ dst,
                                                 int* __restrict__ cnt, int E) {
    int e = blockIdx.x * 256 + threadIdx.x;
    if (e < E) atomicAdd(&cnt[dst[e]], 1);
}

__global__ __launch_bounds__(256) void calc_dinv(const int* __restrict__ cnt,
                                                 float* __restrict__ dinv,
                                                 float* __restrict__ rdinv, int N) {
    int n = blockIdx.x * 256 + threadIdx.x;
    if (n < N) {
        float c = (float)cnt[n] + 1.0f;
        dinv[n] = rsqrtf(c);
        rdinv[n] = sqrtf(c);
    }
}

__global__ __launch_bounds__(SCAN_B) void scan_block(const int* __restrict__ cnt,
                                                     int* __restrict__ out,
                                                     int* __restrict__ bsum, int N) {
    __shared__ int tmp[SCAN_B];
    int t = threadIdx.x;
    int gbase = blockIdx.x * SCAN_B;
    int v = (gbase + t < N) ? cnt[gbase + t] : 0;
    tmp[t] = v;
    __syncthreads();
    for (int off = 1; off < SCAN_B; off <<= 1) {
        int x = (t >= off) ? tmp[t - off] : 0;
        __syncthreads();
        tmp[t] += x;
        __syncthreads();
    }
    int incl = tmp[t];
    if (gbase + t < N) out[gbase + t] = incl - v;  // exclusive
    if (t == SCAN_B - 1) bsum[blockIdx.x] = incl;
}

__global__ __launch_bounds__(256) void scan_add(int* __restrict__ ptr,
                                                const int* __restrict__ boff,
                                                int* __restrict__ cursor, int N, int E) {
    int i = blockIdx.x * 256 + threadIdx.x;
    if (i < N) {
        int v = ptr[i] + boff[i / SCAN_B];
        ptr[i] = v;
        cursor[i] = v;
    }
    if (i == 0) ptr[N] = E;
}

__global__ __launch_bounds__(256) void fill_csr(const int* __restrict__ src,
                                                const int* __restrict__ dst,
                                                int* __restrict__ cursor,
                                                int* __restrict__ sorted, int E) {
    int e = blockIdx.x * 256 + threadIdx.x;
    if (e < E) {
        int p = atomicAdd(&cursor[dst[e]], 1);
        sorted[p] = src[e];
    }
}

// q[n] = Agg(1)[n] = dinv[n]*(sum_nbr dinv[src] + dinv[n])
__global__ __launch_bounds__(256) void qsum_k(const int* __restrict__ ptr,
                                              const int* __restrict__ srcs,
                                              const float* __restrict__ dinv,
                                              float* __restrict__ q, int N) {
    int n = blockIdx.x * 256 + threadIdx.x;
    if (n >= N) return;
    float s = dinv[n];
    int b = ptr[n], e = ptr[n + 1];
    for (int i = b; i < e; i++) s += dinv[srcs[i]];
    q[n] = dinv[n] * s;
}

// actd0 = fp16(x * dinv[n])
__global__ __launch_bounds__(256) void prep_xd(const float* __restrict__ x,
                                               const float* __restrict__ dinv,
                                               ushort* __restrict__ actd, int N16) {
    int p = blockIdx.x * 256 + threadIdx.x;
    if (p >= N16) return;
    int n = p >> 4;
    float d = dinv[n];
    float4 v = reinterpret_cast<const float4*>(x)[p];
    ushort4 o;
    o.x = f2h(v.x * d);
    o.y = f2h(v.y * d);
    o.z = f2h(v.z * d);
    o.w = f2h(v.w * d);
    reinterpret_cast<ushort4*>(actd)[p] = o;
}

// W fragment prep: wfrag[((h*4+c)*64+lane)*8+i] = fp16(W[k][j] * A[k]),
// k = h*32 + (lane>>4)*8 + i, j = c*16 + (lane&15)   (B-frag layout for 16x16x32)
__global__ __launch_bounds__(256) void wprep(const float* __restrict__ W,
                                             const float* __restrict__ Aaf,
                                             ushort* __restrict__ wfrag) {
    int idx = blockIdx.x * 256 + threadIdx.x;  // 0..4095
    if (idx >= 4096) return;
    int i = idx & 7;
    int lane = (idx >> 3) & 63;
    int hc = idx >> 9;  // 0..7
    int h = hc >> 2, c = hc & 3;
    int k = h * 32 + (lane >> 4) * 8 + i;
    int j = c * 16 + (lane & 15);
    float w = W[k * 64 + j];
    if (Aaf) w *= Aaf[k];
    wfrag[idx] = f2h(w);
}

// ---------------- per-layer kernels ----------------

// 2 nodes per wave (half = lane>>5), ushort2 per lane (features 2l, 2l+1).
// zh[n] = fp16( dinv[n] * (actd[n] + sum_{src} actd[src]) );
// optional BN stats of actd*rdinv.
__global__ __launch_bounds__(256) void agg_gather2(const ushort* __restrict__ actd,
                                                   const int* __restrict__ ptr,
                                                   const int* __restrict__ srcs,
                                                   const float* __restrict__ dinv,
                                                   const float* __restrict__ rdinv,
                                                   ushort* __restrict__ zh,
                                                   float* __restrict__ ssum,
                                                   float* __restrict__ sssq,
                                                   int N, int E) {
    __shared__ float red[2][4][64];
    int lane = threadIdx.x & 63;
    int wv = threadIdx.x >> 6;
    int l = lane & 31;
    int half = lane >> 5;
    int Np = (N + 1) >> 1;
    int Em1 = E - 1;
    const bool do_stats = (ssum != nullptr);
    float2 ps = make_float2(0.f, 0.f), pq = make_float2(0.f, 0.f);
    for (int p = blockIdx.x * 4 + wv; p < Np; p += gridDim.x * 4) {
        int n = 2 * p + half;
        bool valid = n < N;
        int s = 0, d = 0;
        if (valid) {
            s = ptr[n];
            d = ptr[n + 1] - s;
        }
        uint self = valid
            ? *reinterpret_cast<const uint*>(actd + ((size_t)n << 6) + (l << 1))
            : 0u;
        float2 acc = up2(self);
        if (do_stats && valid) {
            float r = rdinv[n];
            float ax = acc.x * r, ay = acc.y * r;
            ps.x += ax; ps.y += ay;
            pq.x += ax * ax; pq.y += ay * ay;
        }
        int d0 = __shfl(d, 0);
        int d1 = __shfl(d, 32);
        int dmax = max(d0, d1);
#define GSTEP(j)                                                                    \
        {                                                                           \
            int ii = it + (j);                                                      \
            int idx = min(s + ii, Em1);                                             \
            int uu = srcs[idx];                                                     \
            uint vv = *reinterpret_cast<const uint*>(actd + ((size_t)uu << 6) +     \
                                                     (l << 1));                     \
            float w = (ii < d) ? 1.0f : 0.0f;                                       \
            float2 f = up2(vv);                                                     \
            acc.x = fmaf(w, f.x, acc.x);                                            \
            acc.y = fmaf(w, f.y, acc.y);                                            \
        }
        for (int it = 0; it < dmax; it += 8) {
            GSTEP(0) GSTEP(1) GSTEP(2) GSTEP(3)
            GSTEP(4) GSTEP(5) GSTEP(6) GSTEP(7)
        }
#undef GSTEP
        if (valid) {
            float dn = dinv[n];
            uint pk = (uint)f2h(acc.x * dn) | ((uint)f2h(acc.y * dn) << 16);
            *reinterpret_cast<uint*>(zh + ((size_t)n << 6) + (l << 1)) = pk;
        }
    }
    if (do_stats) {
        ps.x += __shfl_xor(ps.x, 32);
        ps.y += __shfl_xor(ps.y, 32);
        pq.x += __shfl_xor(pq.x, 32);
        pq.y += __shfl_xor(pq.y, 32);
        if (half == 0) {
            red[0][wv][2 * l + 0] = ps.x;
            red[0][wv][2 * l + 1] = ps.y;
            red[1][wv][2 * l + 0] = pq.x;
            red[1][wv][2 * l + 1] = pq.y;
        }
        __syncthreads();
        if (wv == 0) {
            float t0 = red[0][0][lane] + red[0][1][lane] + red[0][2][lane] + red[0][3][lane];
            float t1 = red[1][0][lane] + red[1][1][lane] + red[1][2][lane] + red[1][3][lane];
            atomicAdd(&ssum[lane], t0);
            atomicAdd(&sssq[lane], t1);
        }
    }
}

// MFMA GEMM: block = 64-node tile, 4 waves; wave wv computes rows wv*16..wv*16+15.
// pre[n][j] = sum_k zh[n][k]*wfrag(k,j) + q[n]*u[j] + b[j]; act = MODE(pre).
// OUT_HALF: write fp16(act*dinv); else f32 act + fused BN stats.
template <int MODE, bool HAS_AFF, bool OUT_HALF>
__global__ __launch_bounds__(256) void gemm_mfma(const ushort* __restrict__ zh,
                                                 const ushort* __restrict__ wfrag,
                                                 const float* __restrict__ bias,
                                                 const float* __restrict__ u,
                                                 const float* __restrict__ q,
                                                 const float* __restrict__ dinv,
                                                 ushort* __restrict__ outh,
                                                 float* __restrict__ outf,
                                                 float* __restrict__ ssum,
                                                 float* __restrict__ sssq, int N) {
    int tid = threadIdx.x;
    int lane = tid & 63;
    int wv = tid >> 6;
    int l15 = lane & 15;
    int lg = lane >> 4;  // 0..3
    int tb = blockIdx.x * 64;

    // A fragments: row = tb + wv*16 + l15, k = h*32 + lg*8 + i
    const ushort* zrow = zh + ((size_t)(tb + wv * 16 + l15) << 6) + (lg << 3);
    f16x8 a0 = *reinterpret_cast<const f16x8*>(zrow);
    f16x8 a1 = *reinterpret_cast<const f16x8*>(zrow + 32);

    const f16x8* wf = reinterpret_cast<const f16x8*>(wfrag) + lane;

    f32x4 acc[4];
#pragma unroll
    for (int c = 0; c < 4; c++) {
        f32x4 t = {0.f, 0.f, 0.f, 0.f};
        t = __builtin_amdgcn_mfma_f32_16x16x32_f16(a0, wf[(0 * 4 + c) * 64], t, 0, 0, 0);
        t = __builtin_amdgcn_mfma_f32_16x16x32_f16(a1, wf[(1 * 4 + c) * 64], t, 0, 0, 0);
        acc[c] = t;
    }

    // epilogue: D[row][col], row = tb + wv*16 + lg*4 + r, col = c*16 + l15
    int rowbase = tb + wv * 16 + lg * 4;
    float qv[4], dv[4];
    bool vld[4];
#pragma unroll
    for (int r = 0; r < 4; r++) {
        int row = rowbase + r;
        vld[r] = row < N;
        qv[r] = (HAS_AFF && vld[r]) ? q[row] : 0.f;
        dv[r] = (OUT_HALF && vld[r]) ? dinv[row] : 0.f;
    }
    float sa[4], sq[4];
#pragma unroll
    for (int c = 0; c < 4; c++) { sa[c] = 0.f; sq[c] = 0.f; }

#pragma unroll
    for (int c = 0; c < 4; c++) {
        int col = c * 16 + l15;
        float bcol = bias[col];
        float ucol = HAS_AFF ? u[col] : 0.f;
#pragma unroll
        for (int r = 0; r < 4; r++) {
            if (!vld[r]) continue;
            float o = acc[c][r] + bcol;
            if (HAS_AFF) o = fmaf(qv[r], ucol, o);
            float a = (MODE == 0) ? sigmoidf_(o)
                                  : ((MODE == 1) ? o : sigmoidf_(0.5f * o));
            int row = rowbase + r;
            if (OUT_HALF) {
                outh[((size_t)row << 6) + col] = f2h(a * dv[r]);
            } else {
                outf[((size_t)row << 6) + col] = a;
                sa[c] += a;
                sq[c] += a * a;
            }
        }
    }

    if (!OUT_HALF) {
        __shared__ float red[2][4][4][16];  // [sum|sq][wv][c][l15]
#pragma unroll
        for (int c = 0; c < 4; c++) {
            sa[c] += __shfl_xor(sa[c], 16);
            sa[c] += __shfl_xor(sa[c], 32);
            sq[c] += __shfl_xor(sq[c], 16);
            sq[c] += __shfl_xor(sq[c], 32);
        }
        if (lg == 0) {
#pragma unroll
            for (int c = 0; c < 4; c++) {
                red[0][wv][c][l15] = sa[c];
                red[1][wv][c][l15] = sq[c];
            }
        }
        __syncthreads();
        if (wv == 0) {
            int c = lane >> 4, l = lane & 15;
            float t0 = red[0][0][c][l] + red[0][1][c][l] + red[0][2][c][l] + red[0][3][c][l];
            float t1 = red[1][0][c][l] + red[1][1][c][l] + red[1][2][c][l] + red[1][3][c][l];
            atomicAdd(&ssum[lane], t0);
            atomicAdd(&sssq[lane], t1);
        }
    }
}

// A[c] = rsqrt(var+eps)*gamma[c];  C[c] = beta[c] - mean*A[c]
__global__ __launch_bounds__(64) void finalize_aff(const float* __restrict__ ssum,
                                                   const float* __restrict__ sssq,
                                                   const float* __restrict__ gamma,
                                                   const float* __restrict__ beta,
                                                   float* __restrict__ A,
                                                   float* __restrict__ C, float invN) {
    int c = threadIdx.x;
    float m = ssum[c] * invN;
    float var = sssq[c] * invN - m * m;
    float rs = rsqrtf(var + 1e-4f);
    float a = rs * gamma[c];
    A[c] = a;
    C[c] = fmaf(-m, a, beta[c]);
}

// u[j] = sum_k C[k]*W[k][j]
__global__ __launch_bounds__(64) void compute_u(const float* __restrict__ C,
                                                const float* __restrict__ W,
                                                float* __restrict__ u) {
    int j = threadIdx.x;
    float s = 0.f;
    for (int k = 0; k < 64; k++) s = fmaf(C[k], W[k * 64 + j], s);
    u[j] = s;
}

__global__ __launch_bounds__(256) void bn_apply_h(const ushort* __restrict__ actd,
                                                  const float* __restrict__ rdinv,
                                                  const float* __restrict__ A,
                                                  const float* __restrict__ C,
                                                  float* __restrict__ out, int N16) {
    int p = blockIdx.x * 256 + threadIdx.x;
    if (p >= N16) return;
    int n = p >> 4;
    int cb = (p & 15) * 4;
    float r = rdinv[n];
    ushort4 v = reinterpret_cast<const ushort4*>(actd)[p];
    float4 o;
    o.x = fmaf(h2f(v.x) * r, A[cb + 0], C[cb + 0]);
    o.y = fmaf(h2f(v.y) * r, A[cb + 1], C[cb + 1]);
    o.z = fmaf(h2f(v.z) * r, A[cb + 2], C[cb + 2]);
    o.w = fmaf(h2f(v.w) * r, A[cb + 3], C[cb + 3]);
    reinterpret_cast<float4*>(out)[p] = o;
}

__global__ __launch_bounds__(256) void bn_apply_f32(const float* __restrict__ act,
                                                    const float* __restrict__ A,
                                                    const float* __restrict__ C,
                                                    float* __restrict__ out, int N16) {
    int p = blockIdx.x * 256 + threadIdx.x;
    if (p >= N16) return;
    int cb = (p & 15) * 4;
    float4 v = reinterpret_cast<const float4*>(act)[p];
    float4 o;
    o.x = fmaf(v.x, A[cb + 0], C[cb + 0]);
    o.y = fmaf(v.y, A[cb + 1], C[cb + 1]);
    o.z = fmaf(v.z, A[cb + 2], C[cb + 2]);
    o.w = fmaf(v.w, A[cb + 3], C[cb + 3]);
    reinterpret_cast<float4*>(out)[p] = o;
}

// ---------------- launch ----------------

extern "C" void kernel_launch(void* const* d_in, const int* in_sizes, int n_in,
                              void* d_out, int out_size, void* d_ws, size_t ws_size,
                              hipStream_t stream) {
    const int N = in_sizes[0] / D;
    const int E = in_sizes[1] / 2;

    const float* x = (const float*)d_in[0];
    const int* ei = (const int*)d_in[1];
    const int* src_in = ei;
    const int* dst_in = ei + E;
    const float* encW = (const float*)d_in[3];
    const float* encb = (const float*)d_in[4];
    const float* encg = (const float*)d_in[5];
    const float* encbe = (const float*)d_in[6];
    const float* attW = (const float*)d_in[7];
    const float* attb = (const float*)d_in[8];
    const float* attg = (const float*)d_in[9];
    const float* attbe = (const float*)d_in[10];
    const float* strW = (const float*)d_in[11];
    const float* strb = (const float*)d_in[12];
    const float* strg = (const float*)d_in[13];
    const float* strbe = (const float*)d_in[14];

    char* ws = (char*)d_ws;
    size_t off = 0;
    auto alloc = [&](size_t bytes) -> char* {
        char* p = ws + off;
        off += (bytes + 255) & ~(size_t)255;
        return p;
    };
    int* cnt = (int*)alloc((size_t)N * 4);
    int* csr = (int*)alloc((size_t)(N + 1) * 4);
    int* cursor = (int*)alloc((size_t)N * 4);
    int* sorted = (int*)alloc((size_t)E * 4);
    int* bsum = (int*)alloc(1024 * 4);
    int* boff = (int*)alloc(1024 * 4);
    int* dummy = (int*)alloc(1024 * 4);
    float* dinv = (float*)alloc((size_t)N * 4);
    float* rdinv = (float*)alloc((size_t)N * 4);
    float* q = (float*)alloc((size_t)N * 4);
    float* stats = (float*)alloc(6 * 128 * 4);
    float* aff = (float*)alloc(6 * 128 * 4);
    float* ubuf = (float*)alloc(6 * 64 * 4);
    ushort* wf = (ushort*)alloc(6 * 4096 * 2);
    ushort* zh = (ushort*)alloc((size_t)(N + 64) * D * 2);  // +64 pad rows for tail tile
    float* fbuf = (float*)alloc((size_t)N * D * 4);
    ushort* hA = (ushort*)alloc((size_t)N * D * 2);
    ushort* hB = (ushort*)alloc((size_t)N * D * 2);

    float* out_str = (float*)d_out;
    float* out_att = out_str + (size_t)N * D;
    float* out_enc = out_att + (size_t)N * D;

    hipMemsetAsync(cnt, 0, (size_t)N * 4, stream);
    hipMemsetAsync(stats, 0, 6 * 128 * 4, stream);

    int gE = (E + 255) / 256;
    int gN = (N + 255) / 256;
    int gT = (N + 63) / 64;  // gemm tiles
    int nsb = (N + SCAN_B - 1) / SCAN_B;
    int N16 = N * 16;
    int g16 = (N16 + 255) / 256;
    float invN = 1.0f / (float)N;

    // ---- CSR build + norm precompute ----
    count_deg<<<gE, 256, 0, stream>>>(dst_in, cnt, E);
    calc_dinv<<<gN, 256, 0, stream>>>(cnt, dinv, rdinv, N);
    scan_block<<<nsb, SCAN_B, 0, stream>>>(cnt, csr, bsum, N);
    scan_block<<<1, SCAN_B, 0, stream>>>(bsum, boff, dummy, nsb);
    scan_add<<<gN, 256, 0, stream>>>(csr, boff, cursor, N, E);
    fill_csr<<<gE, 256, 0, stream>>>(src_in, dst_in, cursor, sorted, E);
    qsum_k<<<gN, 256, 0, stream>>>(csr, sorted, dinv, q, N);

    float* A0 = aff + 0 * 128; float* C0 = A0 + 64;
    float* A1 = aff + 1 * 128; float* C1 = A1 + 64;
    float* A2 = aff + 2 * 128; float* C2 = A2 + 64;
    float* A3 = aff + 3 * 128; float* C3 = A3 + 64;
    float* A4 = aff + 4 * 128; float* C4 = A4 + 64;
    float* A5 = aff + 5 * 128; float* C5 = A5 + 64;
    ushort* wf0 = wf + 0 * 4096;
    ushort* wf1 = wf + 1 * 4096;
    ushort* wf2 = wf + 2 * 4096;
    ushort* wf3 = wf + 3 * 4096;
    ushort* wf4 = wf + 4 * 4096;
    ushort* wf5 = wf + 5 * 4096;

    // ---- encoder layer 1 ----
    prep_xd<<<g16, 256, 0, stream>>>(x, dinv, hA, N16);
    wprep<<<16, 256, 0, stream>>>(encW, nullptr, wf0);
    agg_gather2<<<2048, 256, 0, stream>>>(hA, csr, sorted, dinv, rdinv, zh,
                                          nullptr, nullptr, N, E);
    gemm_mfma<0, false, true><<<gT, 256, 0, stream>>>(zh, wf0, encb, nullptr, q,
                                                      dinv, hB, nullptr,
                                                      nullptr, nullptr, N);
    // ---- encoder layer 2 ----
    agg_gather2<<<2048, 256, 0, stream>>>(hB, csr, sorted, dinv, rdinv, zh,
                                          stats + 0, stats + 64, N, E);
    finalize_aff<<<1, 64, 0, stream>>>(stats + 0, stats + 64, encg, encbe, A0, C0, invN);
    compute_u<<<1, 64, 0, stream>>>(C0, encW + 4096, ubuf + 0);
    wprep<<<16, 256, 0, stream>>>(encW + 4096, A0, wf1);
    gemm_mfma<0, true, true><<<gT, 256, 0, stream>>>(zh, wf1, encb + 64, ubuf + 0,
                                                     q, dinv, hA, nullptr,
                                                     nullptr, nullptr, N);
    // ---- z2 = Agg(x_enc-act), shared by att1 & str1; also enc2 stats ----
    agg_gather2<<<2048, 256, 0, stream>>>(hA, csr, sorted, dinv, rdinv, zh,
                                          stats + 128, stats + 192, N, E);
    finalize_aff<<<1, 64, 0, stream>>>(stats + 128, stats + 192, encg + 64,
                                       encbe + 64, A1, C1, invN);
    compute_u<<<1, 64, 0, stream>>>(C1, attW, ubuf + 64);
    compute_u<<<1, 64, 0, stream>>>(C1, strW, ubuf + 128);
    wprep<<<16, 256, 0, stream>>>(attW, A1, wf2);
    wprep<<<16, 256, 0, stream>>>(strW, A1, wf3);
    bn_apply_h<<<g16, 256, 0, stream>>>(hA, rdinv, A1, C1, out_enc, N16);
    gemm_mfma<0, true, true><<<gT, 256, 0, stream>>>(zh, wf2, attb, ubuf + 64,
                                                     q, dinv, hB, nullptr,
                                                     nullptr, nullptr, N);
    gemm_mfma<0, true, true><<<gT, 256, 0, stream>>>(zh, wf3, strb, ubuf + 128,
                                                     q, dinv, hA, nullptr,
                                                     nullptr, nullptr, N);
    // ---- attribute layer 2 (terminal, linear; BN stats fused) ----
    agg_gather2<<<2048, 256, 0, stream>>>(hB, csr, sorted, dinv, rdinv, zh,
                                          stats + 256, stats + 320, N, E);
    finalize_aff<<<1, 64, 0, stream>>>(stats + 256, stats + 320, attg, attbe,
                                       A2, C2, invN);
    compute_u<<<1, 64, 0, stream>>>(C2, attW + 4096, ubuf + 192);
    wprep<<<16, 256, 0, stream>>>(attW + 4096, A2, wf4);
    gemm_mfma<1, true, false><<<gT, 256, 0, stream>>>(zh, wf4, attb + 64, ubuf + 192,
                                                      q, dinv, nullptr, fbuf,
                                                      stats + 384, stats + 448, N);
    finalize_aff<<<1, 64, 0, stream>>>(stats + 384, stats + 448, attg + 64,
                                       attbe + 64, A3, C3, invN);
    bn_apply_f32<<<g16, 256, 0, stream>>>(fbuf, A3, C3, out_att, N16);
    // ---- structure layer 2 (terminal, sigmoid(0.5x); BN stats fused) ----
    agg_gather2<<<2048, 256, 0, stream>>>(hA, csr, sorted, dinv, rdinv, zh,
                                          stats + 512, stats + 576, N, E);
    finalize_aff<<<1, 64, 0, stream>>>(stats + 512, stats + 576, strg, strbe,
                                       A4, C4, invN);
    compute_u<<<1, 64, 0, stream>>>(C4, strW + 4096, ubuf + 320);
    wprep<<<16, 256, 0, stream>>>(strW + 4096, A4, wf5);
    gemm_mfma<2, true, false><<<gT, 256, 0, stream>>>(zh, wf5, strb + 64, ubuf + 320,
                                                      q, dinv, nullptr, fbuf,
                                                      stats + 640, stats + 704, N);
    finalize_aff<<<1, 64, 0, stream>>>(stats + 640, stats + 704, strg + 64,
                                       strbe + 64, A5, C5, invN);
    bn_apply_f32<<<g16, 256, 0, stream>>>(fbuf, A5, C5, out_str, N16);
}

// Round 7
// 651.415 us; speedup vs baseline: 5.7249x; 1.1785x over previous
//
#include <hip/hip_runtime.h>

#define D 64
#define BCH 4096

typedef __attribute__((ext_vector_type(8))) _Float16 f16x8;
typedef __attribute__((ext_vector_type(4))) float f32x4;

__device__ __forceinline__ float sigmoidf_(float x) {
    return 1.0f / (1.0f + __expf(-x));
}
__device__ __forceinline__ float h2f(ushort u) {
    _Float16 h;
    __builtin_memcpy(&h, &u, 2);
    return (float)h;
}
__device__ __forceinline__ ushort f2h(float f) {
    _Float16 h = (_Float16)f;
    ushort u;
    __builtin_memcpy(&u, &h, 2);
    return u;
}
__device__ __forceinline__ float2 up2(uint v) {
    float2 r;
    r.x = h2f((ushort)(v & 0xffffu));
    r.y = h2f((ushort)(v >> 16));
    return r;
}

// ---------------- CSR build: 2-level bucket sort ----------------
// bucket = dst >> 10 (1024 nodes per bucket).

__global__ __launch_bounds__(256) void bin_edges(const int* __restrict__ src,
                                                 const int* __restrict__ dst,
                                                 int* __restrict__ bcur,
                                                 int* __restrict__ binsrc,
                                                 int* __restrict__ bindst,
                                                 int CAP, int E) {
    __shared__ int lsrc[BCH], ldst[BCH];
    __shared__ int hist[128], base[128];
    int t = threadIdx.x;
    int e0 = blockIdx.x * BCH;
    if (t < 128) hist[t] = 0;
    __syncthreads();
    for (int k = t; k < BCH; k += 256) {
        int e = e0 + k;
        int d_ = -1, s_ = 0;
        if (e < E) {
            s_ = src[e];
            d_ = dst[e];
            atomicAdd(&hist[d_ >> 10], 1);
        }
        lsrc[k] = s_;
        ldst[k] = d_;
    }
    __syncthreads();
    if (t < 128) {
        int c = hist[t];
        base[t] = (c > 0) ? atomicAdd(&bcur[t], c) : 0;
        hist[t] = 0;
    }
    __syncthreads();
    for (int k = t; k < BCH; k += 256) {
        int d_ = ldst[k];
        if (d_ >= 0) {
            int b = d_ >> 10;
            int p = base[b] + atomicAdd(&hist[b], 1);
            binsrc[(size_t)b * CAP + p] = lsrc[k];
            bindst[(size_t)b * CAP + p] = d_;
        }
    }
}

__global__ __launch_bounds__(128) void scan_nb(const int* __restrict__ bcur,
                                               int* __restrict__ boff,
                                               int* __restrict__ csr,
                                               int NB, int N, int E) {
    __shared__ int tmp[128];
    int t = threadIdx.x;
    int v = (t < NB) ? bcur[t] : 0;
    tmp[t] = v;
    __syncthreads();
    for (int o = 1; o < 128; o <<= 1) {
        int x = (t >= o) ? tmp[t - o] : 0;
        __syncthreads();
        tmp[t] += x;
        __syncthreads();
    }
    if (t < NB) boff[t] = tmp[t] - v;  // exclusive
    if (t == 0) csr[N] = E;
}

// one block per bucket: per-node hist -> scan -> csr/dinv -> localized scatter
__global__ __launch_bounds__(256) void build_csr(const int* __restrict__ binsrc,
                                                 const int* __restrict__ bindst,
                                                 const int* __restrict__ bcur,
                                                 const int* __restrict__ boff,
                                                 int* __restrict__ csr,
                                                 int* __restrict__ sorted,
                                                 float* __restrict__ dinv,
                                                 float* __restrict__ rdinv,
                                                 int CAP, int N) {
    __shared__ int hist[1024];
    __shared__ int part[256];
    int t = threadIdx.x;
    int b = blockIdx.x;
    int nb0 = b << 10;
    int cnt = bcur[b];
    int e0 = boff[b];
    const int* bs = binsrc + (size_t)b * CAP;
    const int* bd = bindst + (size_t)b * CAP;
    for (int k = t; k < 1024; k += 256) hist[k] = 0;
    __syncthreads();
    for (int k = t; k < cnt; k += 256) atomicAdd(&hist[bd[k] - nb0], 1);
    __syncthreads();
    int v0 = hist[4 * t], v1 = hist[4 * t + 1], v2 = hist[4 * t + 2], v3 = hist[4 * t + 3];
    part[t] = v0 + v1 + v2 + v3;
    __syncthreads();
    for (int o = 1; o < 256; o <<= 1) {
        int x = (t >= o) ? part[t - o] : 0;
        __syncthreads();
        part[t] += x;
        __syncthreads();
    }
    int run = (t > 0) ? part[t - 1] : 0;
    int pre[4];
    pre[0] = run;
    pre[1] = run + v0;
    pre[2] = run + v0 + v1;
    pre[3] = run + v0 + v1 + v2;
    int deg[4] = {v0, v1, v2, v3};
    __syncthreads();
    hist[4 * t + 0] = e0 + pre[0];
    hist[4 * t + 1] = e0 + pre[1];
    hist[4 * t + 2] = e0 + pre[2];
    hist[4 * t + 3] = e0 + pre[3];
#pragma unroll
    for (int j = 0; j < 4; j++) {
        int node = nb0 + 4 * t + j;
        if (node < N) {
            csr[node] = e0 + pre[j];
            float c = (float)deg[j] + 1.0f;
            dinv[node] = rsqrtf(c);
            rdinv[node] = sqrtf(c);
        }
    }
    __syncthreads();
    for (int k = t; k < cnt; k += 256) {
        int d_ = bd[k];
        int p = atomicAdd(&hist[d_ - nb0], 1);
        sorted[p] = bs[k];
    }
}

// ---------------- prep ----------------

__global__ __launch_bounds__(256) void prep_xd(const float* __restrict__ x,
                                               const float* __restrict__ dinv,
                                               ushort* __restrict__ actd, int N16) {
    int p = blockIdx.x * 256 + threadIdx.x;
    if (p >= N16) return;
    int n = p >> 4;
    float d = dinv[n];
    float4 v = reinterpret_cast<const float4*>(x)[p];
    ushort4 o;
    o.x = f2h(v.x * d);
    o.y = f2h(v.y * d);
    o.z = f2h(v.z * d);
    o.w = f2h(v.w * d);
    reinterpret_cast<ushort4*>(actd)[p] = o;
}

// W fragment prep: wfrag[((h*4+c)*64+lane)*8+i] = fp16(W[k][j] * A[k])
__global__ __launch_bounds__(256) void wprep(const float* __restrict__ W,
                                             const float* __restrict__ Aaf,
                                             ushort* __restrict__ wfrag) {
    int idx = blockIdx.x * 256 + threadIdx.x;
    if (idx >= 4096) return;
    int i = idx & 7;
    int lane = (idx >> 3) & 63;
    int hc = idx >> 9;
    int h = hc >> 2, c = hc & 3;
    int k = h * 32 + (lane >> 4) * 8 + i;
    int j = c * 16 + (lane & 15);
    float w = W[k * 64 + j];
    if (Aaf) w *= Aaf[k];
    wfrag[idx] = f2h(w);
}

// ---------------- aggregation ----------------

// one node per wave; wave halves process alternating neighbors.
// zh[n] = fp16(dinv[n]*(actd[n] + sum actd[src])); optional stats / q.
__global__ __launch_bounds__(256) void agg_g(const ushort* __restrict__ actd,
                                             const int* __restrict__ ptr,
                                             const int* __restrict__ srcs,
                                             const float* __restrict__ dinv,
                                             const float* __restrict__ rdinv,
                                             ushort* __restrict__ zh,
                                             float* __restrict__ ssum,
                                             float* __restrict__ sssq,
                                             float* __restrict__ qout, int N) {
    __shared__ float red[2][4][64];
    int lane = threadIdx.x & 63;
    int wv = threadIdx.x >> 6;
    int l = lane & 31, h = lane >> 5;
    const bool do_stats = (ssum != nullptr);
    const bool do_q = (qout != nullptr);
    float2 ps = make_float2(0.f, 0.f), pq = make_float2(0.f, 0.f);
    for (int n = blockIdx.x * 4 + wv; n < N; n += gridDim.x * 4) {
        int s = ptr[n], e = ptr[n + 1];
        uint selfu = *reinterpret_cast<const uint*>(actd + ((size_t)n << 6) + (l << 1));
        float2 sf = up2(selfu);
        float2 acc = (h == 0) ? sf : make_float2(0.f, 0.f);
        float dn = dinv[n];
        if (do_stats && h == 0) {
            float r = rdinv[n];
            float ax = sf.x * r, ay = sf.y * r;
            ps.x += ax; ps.y += ay;
            pq.x += ax * ax; pq.y += ay * ay;
        }
        float qa = 0.f;
        int i = s + h;
        for (; i + 6 < e; i += 8) {
            int u0 = srcs[i], u1 = srcs[i + 2], u2 = srcs[i + 4], u3 = srcs[i + 6];
            uint w0 = *reinterpret_cast<const uint*>(actd + ((size_t)u0 << 6) + (l << 1));
            uint w1 = *reinterpret_cast<const uint*>(actd + ((size_t)u1 << 6) + (l << 1));
            uint w2 = *reinterpret_cast<const uint*>(actd + ((size_t)u2 << 6) + (l << 1));
            uint w3 = *reinterpret_cast<const uint*>(actd + ((size_t)u3 << 6) + (l << 1));
            if (do_q && l == 0) qa += (dinv[u0] + dinv[u1]) + (dinv[u2] + dinv[u3]);
            float2 f0 = up2(w0), f1 = up2(w1), f2 = up2(w2), f3 = up2(w3);
            acc.x += (f0.x + f1.x) + (f2.x + f3.x);
            acc.y += (f0.y + f1.y) + (f2.y + f3.y);
        }
        for (; i < e; i += 2) {
            int u = srcs[i];
            uint w = *reinterpret_cast<const uint*>(actd + ((size_t)u << 6) + (l << 1));
            if (do_q && l == 0) qa += dinv[u];
            float2 f = up2(w);
            acc.x += f.x;
            acc.y += f.y;
        }
        acc.x += __shfl_xor(acc.x, 32);
        acc.y += __shfl_xor(acc.y, 32);
        if (do_q) {
            float qo = qa + __shfl(qa, 32);
            if (lane == 0) qout[n] = dn * (dn + qo);
        }
        if (h == 0) {
            uint pk = (uint)f2h(acc.x * dn) | ((uint)f2h(acc.y * dn) << 16);
            *reinterpret_cast<uint*>(zh + ((size_t)n << 6) + (l << 1)) = pk;
        }
    }
    if (do_stats) {
        if (h == 0) {
            red[0][wv][2 * l + 0] = ps.x;
            red[0][wv][2 * l + 1] = ps.y;
            red[1][wv][2 * l + 0] = pq.x;
            red[1][wv][2 * l + 1] = pq.y;
        }
        __syncthreads();
        if (wv == 0) {
            float t0 = red[0][0][lane] + red[0][1][lane] + red[0][2][lane] + red[0][3][lane];
            float t1 = red[1][0][lane] + red[1][1][lane] + red[1][2][lane] + red[1][3][lane];
            atomicAdd(&ssum[lane], t0);
            atomicAdd(&sssq[lane], t1);
        }
    }
}

// fused gather over interleaved att|str buffer (256B rows), 1 node/wave.
__global__ __launch_bounds__(256) void agg_dual(const ushort* __restrict__ ab,
                                                const int* __restrict__ ptr,
                                                const int* __restrict__ srcs,
                                                const float* __restrict__ dinv,
                                                const float* __restrict__ rdinv,
                                                ushort* __restrict__ zab,
                                                float* __restrict__ ssA,
                                                float* __restrict__ sqA,
                                                float* __restrict__ ssS,
                                                float* __restrict__ sqS,
                                                int N, int E) {
    __shared__ float red[2][4][128];
    int lane = threadIdx.x & 63;
    int wv = threadIdx.x >> 6;
    int Em1 = E - 1;
    float2 ps = make_float2(0.f, 0.f), pq = make_float2(0.f, 0.f);
    for (int n = blockIdx.x * 4 + wv; n < N; n += gridDim.x * 4) {
        int s = ptr[n], e = ptr[n + 1];
        uint su = *reinterpret_cast<const uint*>(ab + ((size_t)n << 7) + (lane << 1));
        float2 acc = up2(su);
        {
            float r = rdinv[n];
            float ax = acc.x * r, ay = acc.y * r;
            ps.x += ax; ps.y += ay;
            pq.x += ax * ax; pq.y += ay * ay;
        }
        int i = s;
        for (; i + 7 < e; i += 8) {
            int u[8];
#pragma unroll
            for (int j = 0; j < 8; j++) u[j] = srcs[i + j];
#pragma unroll
            for (int j = 0; j < 8; j++) {
                uint v = *reinterpret_cast<const uint*>(ab + ((size_t)u[j] << 7) + (lane << 1));
                float2 f = up2(v);
                acc.x += f.x;
                acc.y += f.y;
            }
        }
        if (i < e) {
#pragma unroll
            for (int j = 0; j < 8; j++) {
                int idx = min(i + j, Em1);
                int u_ = srcs[idx];
                uint v = *reinterpret_cast<const uint*>(ab + ((size_t)u_ << 7) + (lane << 1));
                float w = (i + j < e) ? 1.0f : 0.0f;
                float2 f = up2(v);
                acc.x = fmaf(w, f.x, acc.x);
                acc.y = fmaf(w, f.y, acc.y);
            }
        }
        float dn = dinv[n];
        uint pk = (uint)f2h(acc.x * dn) | ((uint)f2h(acc.y * dn) << 16);
        *reinterpret_cast<uint*>(zab + ((size_t)n << 7) + (lane << 1)) = pk;
    }
    red[0][wv][2 * lane + 0] = ps.x;
    red[0][wv][2 * lane + 1] = ps.y;
    red[1][wv][2 * lane + 0] = pq.x;
    red[1][wv][2 * lane + 1] = pq.y;
    __syncthreads();
    if (wv == 0) {
#pragma unroll
        for (int m0 = 0; m0 < 2; m0++) {
            int m = lane + m0 * 64;
            float t0 = red[0][0][m] + red[0][1][m] + red[0][2][m] + red[0][3][m];
            float t1 = red[1][0][m] + red[1][1][m] + red[1][2][m] + red[1][3][m];
            if (m < 64) {
                atomicAdd(&ssA[m], t0);
                atomicAdd(&sqA[m], t1);
            } else {
                atomicAdd(&ssS[m - 64], t0);
                atomicAdd(&sqS[m - 64], t1);
            }
        }
    }
}

// ---------------- MFMA GEMM ----------------

template <int MODE, bool HAS_AFF, bool OUT_HALF>
__global__ __launch_bounds__(256) void gemm_mfma(const ushort* __restrict__ zh, int is,
                                                 const ushort* __restrict__ wfrag,
                                                 const float* __restrict__ bias,
                                                 const float* __restrict__ u,
                                                 const float* __restrict__ q,
                                                 const float* __restrict__ dinv,
                                                 ushort* __restrict__ outh, int os,
                                                 float* __restrict__ outf,
                                                 float* __restrict__ ssum,
                                                 float* __restrict__ sssq, int N) {
    int tid = threadIdx.x;
    int lane = tid & 63;
    int wv = tid >> 6;
    int l15 = lane & 15;
    int lg = lane >> 4;
    int tb = blockIdx.x * 64;

    const ushort* zrow = zh + (size_t)(tb + wv * 16 + l15) * is + (lg << 3);
    f16x8 a0 = *reinterpret_cast<const f16x8*>(zrow);
    f16x8 a1 = *reinterpret_cast<const f16x8*>(zrow + 32);

    const f16x8* wf = reinterpret_cast<const f16x8*>(wfrag) + lane;

    f32x4 acc[4];
#pragma unroll
    for (int c = 0; c < 4; c++) {
        f32x4 t = {0.f, 0.f, 0.f, 0.f};
        t = __builtin_amdgcn_mfma_f32_16x16x32_f16(a0, wf[(0 * 4 + c) * 64], t, 0, 0, 0);
        t = __builtin_amdgcn_mfma_f32_16x16x32_f16(a1, wf[(1 * 4 + c) * 64], t, 0, 0, 0);
        acc[c] = t;
    }

    int rowbase = tb + wv * 16 + lg * 4;
    float qv[4], dv[4];
    bool vld[4];
#pragma unroll
    for (int r = 0; r < 4; r++) {
        int row = rowbase + r;
        vld[r] = row < N;
        qv[r] = (HAS_AFF && vld[r]) ? q[row] : 0.f;
        dv[r] = (OUT_HALF && vld[r]) ? dinv[row] : 0.f;
    }
    float sa[4], sq[4];
#pragma unroll
    for (int c = 0; c < 4; c++) { sa[c] = 0.f; sq[c] = 0.f; }

#pragma unroll
    for (int c = 0; c < 4; c++) {
        int col = c * 16 + l15;
        float bcol = bias[col];
        float ucol = HAS_AFF ? u[col] : 0.f;
#pragma unroll
        for (int r = 0; r < 4; r++) {
            if (!vld[r]) continue;
            float o = acc[c][r] + bcol;
            if (HAS_AFF) o = fmaf(qv[r], ucol, o);
            float a = (MODE == 0) ? sigmoidf_(o)
                                  : ((MODE == 1) ? o : sigmoidf_(0.5f * o));
            int row = rowbase + r;
            if (OUT_HALF) {
                outh[(size_t)row * os + col] = f2h(a * dv[r]);
            } else {
                outf[((size_t)row << 6) + col] = a;
                sa[c] += a;
                sq[c] += a * a;
            }
        }
    }

    if (!OUT_HALF) {
        __shared__ float red[2][4][4][16];
#pragma unroll
        for (int c = 0; c < 4; c++) {
            sa[c] += __shfl_xor(sa[c], 16);
            sa[c] += __shfl_xor(sa[c], 32);
            sq[c] += __shfl_xor(sq[c], 16);
            sq[c] += __shfl_xor(sq[c], 32);
        }
        if (lg == 0) {
#pragma unroll
            for (int c = 0; c < 4; c++) {
                red[0][wv][c][l15] = sa[c];
                red[1][wv][c][l15] = sq[c];
            }
        }
        __syncthreads();
        if (wv == 0) {
            int c = lane >> 4, l = lane & 15;
            float t0 = red[0][0][c][l] + red[0][1][c][l] + red[0][2][c][l] + red[0][3][c][l];
            float t1 = red[1][0][c][l] + red[1][1][c][l] + red[1][2][c][l] + red[1][3][c][l];
            atomicAdd(&ssum[lane], t0);
            atomicAdd(&sssq[lane], t1);
        }
    }
}

// ---------------- small epilogue kernels ----------------

__global__ __launch_bounds__(64) void finalize_aff(const float* __restrict__ ssum,
                                                   const float* __restrict__ sssq,
                                                   const float* __restrict__ gamma,
                                                   const float* __restrict__ beta,
                                                   float* __restrict__ A,
                                                   float* __restrict__ C, float invN) {
    int c = threadIdx.x;
    float m = ssum[c] * invN;
    float var = sssq[c] * invN - m * m;
    float rs = rsqrtf(var + 1e-4f);
    float a = rs * gamma[c];
    A[c] = a;
    C[c] = fmaf(-m, a, beta[c]);
}

__global__ __launch_bounds__(64) void compute_u(const float* __restrict__ C,
                                                const float* __restrict__ W,
                                                float* __restrict__ u) {
    int j = threadIdx.x;
    float s = 0.f;
    for (int k = 0; k < 64; k++) s = fmaf(C[k], W[k * 64 + j], s);
    u[j] = s;
}

__global__ __launch_bounds__(256) void bn_apply_h(const ushort* __restrict__ actd,
                                                  const float* __restrict__ rdinv,
                                                  const float* __restrict__ A,
                                                  const float* __restrict__ C,
                                                  float* __restrict__ out, int N16) {
    int p = blockIdx.x * 256 + threadIdx.x;
    if (p >= N16) return;
    int n = p >> 4;
    int cb = (p & 15) * 4;
    float r = rdinv[n];
    ushort4 v = reinterpret_cast<const ushort4*>(actd)[p];
    float4 o;
    o.x = fmaf(h2f(v.x) * r, A[cb + 0], C[cb + 0]);
    o.y = fmaf(h2f(v.y) * r, A[cb + 1], C[cb + 1]);
    o.z = fmaf(h2f(v.z) * r, A[cb + 2], C[cb + 2]);
    o.w = fmaf(h2f(v.w) * r, A[cb + 3], C[cb + 3]);
    reinterpret_cast<float4*>(out)[p] = o;
}

__global__ __launch_bounds__(256) void bn_apply_f32(const float* __restrict__ act,
                                                    const float* __restrict__ A,
                                                    const float* __restrict__ C,
                                                    float* __restrict__ out, int N16) {
    int p = blockIdx.x * 256 + threadIdx.x;
    if (p >= N16) return;
    int cb = (p & 15) * 4;
    float4 v = reinterpret_cast<const float4*>(act)[p];
    float4 o;
    o.x = fmaf(v.x, A[cb + 0], C[cb + 0]);
    o.y = fmaf(v.y, A[cb + 1], C[cb + 1]);
    o.z = fmaf(v.z, A[cb + 2], C[cb + 2]);
    o.w = fmaf(v.w, A[cb + 3], C[cb + 3]);
    reinterpret_cast<float4*>(out)[p] = o;
}

// ---------------- launch ----------------

extern "C" void kernel_launch(void* const* d_in, const int* in_sizes, int n_in,
                              void* d_out, int out_size, void* d_ws, size_t ws_size,
                              hipStream_t stream) {
    const int N = in_sizes[0] / D;
    const int E = in_sizes[1] / 2;

    const float* x = (const float*)d_in[0];
    const int* ei = (const int*)d_in[1];
    const int* src_in = ei;
    const int* dst_in = ei + E;
    const float* encW = (const float*)d_in[3];
    const float* encb = (const float*)d_in[4];
    const float* encg = (const float*)d_in[5];
    const float* encbe = (const float*)d_in[6];
    const float* attW = (const float*)d_in[7];
    const float* attb = (const float*)d_in[8];
    const float* attg = (const float*)d_in[9];
    const float* attbe = (const float*)d_in[10];
    const float* strW = (const float*)d_in[11];
    const float* strb = (const float*)d_in[12];
    const float* strg = (const float*)d_in[13];
    const float* strbe = (const float*)d_in[14];

    const int NB = (N + 1023) >> 10;
    int CAP = (E + NB - 1) / NB;
    CAP = CAP + CAP / 8 + 256;
    CAP = (CAP + 255) & ~255;

    char* ws = (char*)d_ws;
    size_t off = 0;
    auto alloc = [&](size_t bytes) -> char* {
        char* p = ws + off;
        off += (bytes + 255) & ~(size_t)255;
        return p;
    };
    int* csr = (int*)alloc((size_t)(N + 1) * 4);
    int* bcur = (int*)alloc(128 * 4);
    int* boff = (int*)alloc(128 * 4);
    float* dinv = (float*)alloc((size_t)N * 4);
    float* rdinv = (float*)alloc((size_t)N * 4);
    float* q = (float*)alloc((size_t)N * 4);
    float* stats = (float*)alloc(6 * 128 * 4);
    float* aff = (float*)alloc(6 * 128 * 4);
    float* ubuf = (float*)alloc(6 * 64 * 4);
    ushort* wf = (ushort*)alloc(6 * 4096 * 2);
    int* sorted = (int*)alloc((size_t)E * 4);
    ushort* zh = (ushort*)alloc((size_t)(N + 64) * 64 * 2);
    // region shared: bins (early) then zAB (late)
    size_t binbytes = 2 * (size_t)NB * CAP * 4;
    size_t zabbytes = (size_t)(N + 64) * 128 * 2;
    char* region = alloc(binbytes > zabbytes ? binbytes : zabbytes);
    int* binsrc = (int*)region;
    int* bindst = binsrc + (size_t)NB * CAP;
    ushort* zab = (ushort*)region;
    float* fbuf = (float*)alloc((size_t)N * 64 * 4);  // aliases hB|hA
    ushort* hB = (ushort*)fbuf;
    ushort* hA = hB + (size_t)N * 64;
    ushort* hAB = (ushort*)alloc((size_t)(N + 64) * 128 * 2);

    float* out_str = (float*)d_out;
    float* out_att = out_str + (size_t)N * D;
    float* out_enc = out_att + (size_t)N * D;

    hipMemsetAsync(bcur, 0, 128 * 4, stream);
    hipMemsetAsync(stats, 0, 6 * 128 * 4, stream);

    int N16 = N * 16;
    int g16 = (N16 + 255) / 256;
    int gT = (N + 63) / 64;
    float invN = 1.0f / (float)N;

    float* A0 = aff + 0 * 128; float* C0 = A0 + 64;
    float* A1 = aff + 1 * 128; float* C1 = A1 + 64;
    float* A2 = aff + 2 * 128; float* C2 = A2 + 64;
    float* A3 = aff + 3 * 128; float* C3 = A3 + 64;
    float* A4 = aff + 4 * 128; float* C4 = A4 + 64;
    float* A5 = aff + 5 * 128; float* C5 = A5 + 64;
    ushort* wf0 = wf + 0 * 4096;
    ushort* wf1 = wf + 1 * 4096;
    ushort* wf2 = wf + 2 * 4096;
    ushort* wf3 = wf + 3 * 4096;
    ushort* wf4 = wf + 4 * 4096;
    ushort* wf5 = wf + 5 * 4096;

    // ---- CSR build ----
    bin_edges<<<(E + BCH - 1) / BCH, 256, 0, stream>>>(src_in, dst_in, bcur,
                                                       binsrc, bindst, CAP, E);
    scan_nb<<<1, 128, 0, stream>>>(bcur, boff, csr, NB, N, E);
    build_csr<<<NB, 256, 0, stream>>>(binsrc, bindst, bcur, boff, csr, sorted,
                                      dinv, rdinv, CAP, N);

    // ---- encoder layer 1 (q fused into first gather) ----
    prep_xd<<<g16, 256, 0, stream>>>(x, dinv, hA, N16);
    wprep<<<16, 256, 0, stream>>>(encW, nullptr, wf0);
    agg_g<<<2048, 256, 0, stream>>>(hA, csr, sorted, dinv, rdinv, zh,
                                    nullptr, nullptr, q, N);
    gemm_mfma<0, false, true><<<gT, 256, 0, stream>>>(zh, 64, wf0, encb, nullptr,
                                                      q, dinv, hB, 64, nullptr,
                                                      nullptr, nullptr, N);
    // ---- encoder layer 2 ----
    agg_g<<<2048, 256, 0, stream>>>(hB, csr, sorted, dinv, rdinv, zh,
                                    stats + 0, stats + 64, nullptr, N);
    finalize_aff<<<1, 64, 0, stream>>>(stats + 0, stats + 64, encg, encbe, A0, C0, invN);
    compute_u<<<1, 64, 0, stream>>>(C0, encW + 4096, ubuf + 0);
    wprep<<<16, 256, 0, stream>>>(encW + 4096, A0, wf1);
    gemm_mfma<0, true, true><<<gT, 256, 0, stream>>>(zh, 64, wf1, encb + 64, ubuf + 0,
                                                     q, dinv, hA, 64, nullptr,
                                                     nullptr, nullptr, N);
    // ---- z2 = Agg(x_enc act), shared by att1 & str1; enc2 stats ----
    agg_g<<<2048, 256, 0, stream>>>(hA, csr, sorted, dinv, rdinv, zh,
                                    stats + 128, stats + 192, nullptr, N);
    finalize_aff<<<1, 64, 0, stream>>>(stats + 128, stats + 192, encg + 64,
                                       encbe + 64, A1, C1, invN);
    compute_u<<<1, 64, 0, stream>>>(C1, attW, ubuf + 64);
    compute_u<<<1, 64, 0, stream>>>(C1, strW, ubuf + 128);
    wprep<<<16, 256, 0, stream>>>(attW, A1, wf2);
    wprep<<<16, 256, 0, stream>>>(strW, A1, wf3);
    bn_apply_h<<<g16, 256, 0, stream>>>(hA, rdinv, A1, C1, out_enc, N16);
    gemm_mfma<0, true, true><<<gT, 256, 0, stream>>>(zh, 64, wf2, attb, ubuf + 64,
                                                     q, dinv, hAB, 128, nullptr,
                                                     nullptr, nullptr, N);
    gemm_mfma<0, true, true><<<gT, 256, 0, stream>>>(zh, 64, wf3, strb, ubuf + 128,
                                                     q, dinv, hAB + 64, 128, nullptr,
                                                     nullptr, nullptr, N);
    // ---- fused att1|str1 gather (+ both stats) ----
    agg_dual<<<2048, 256, 0, stream>>>(hAB, csr, sorted, dinv, rdinv, zab,
                                       stats + 256, stats + 320,
                                       stats + 512, stats + 576, N, E);
    // ---- attribute layer 2 (terminal, linear; BN stats fused) ----
    finalize_aff<<<1, 64, 0, stream>>>(stats + 256, stats + 320, attg, attbe,
                                       A2, C2, invN);
    compute_u<<<1, 64, 0, stream>>>(C2, attW + 4096, ubuf + 192);
    wprep<<<16, 256, 0, stream>>>(attW + 4096, A2, wf4);
    gemm_mfma<1, true, false><<<gT, 256, 0, stream>>>(zab, 128, wf4, attb + 64,
                                                      ubuf + 192, q, dinv,
                                                      nullptr, 0, fbuf,
                                                      stats + 384, stats + 448, N);
    finalize_aff<<<1, 64, 0, stream>>>(stats + 384, stats + 448, attg + 64,
                                       attbe + 64, A3, C3, invN);
    bn_apply_f32<<<g16, 256, 0, stream>>>(fbuf, A3, C3, out_att, N16);
    // ---- structure layer 2 (terminal, sigmoid(0.5x); BN stats fused) ----
    finalize_aff<<<1, 64, 0, stream>>>(stats + 512, stats + 576, strg, strbe,
                                       A4, C4, invN);
    compute_u<<<1, 64, 0, stream>>>(C4, strW + 4096, ubuf + 320);
    wprep<<<16, 256, 0, stream>>>(strW + 4096, A4, wf5);
    gemm_mfma<2, true, false><<<gT, 256, 0, stream>>>(zab + 64, 128, wf5, strb + 64,
                                                      ubuf + 320, q, dinv,
                                                      nullptr, 0, fbuf,
                                                      stats + 640, stats + 704, N);
    finalize_aff<<<1, 64, 0, stream>>>(stats + 640, stats + 704, strg + 64,
                                       strbe + 64, A5, C5, invN);
    bn_apply_f32<<<g16, 256, 0, stream>>>(fbuf, A5, C5, out_str, N16);
}

// Round 8
// 604.866 us; speedup vs baseline: 6.1655x; 1.0770x over previous
//
#include <hip/hip_runtime.h>

#define D 64
#define BCH 4096

typedef __attribute__((ext_vector_type(8))) _Float16 f16x8;
typedef __attribute__((ext_vector_type(4))) float f32x4;

__device__ __forceinline__ float sigmoidf_(float x) {
    return 1.0f / (1.0f + __expf(-x));
}
__device__ __forceinline__ float h2f(ushort u) {
    _Float16 h;
    __builtin_memcpy(&h, &u, 2);
    return (float)h;
}
__device__ __forceinline__ ushort f2h(float f) {
    _Float16 h = (_Float16)f;
    ushort u;
    __builtin_memcpy(&u, &h, 2);
    return u;
}
__device__ __forceinline__ float2 up2(uint v) {
    float2 r;
    r.x = h2f((ushort)(v & 0xffffu));
    r.y = h2f((ushort)(v >> 16));
    return r;
}

// ---------------- CSR build: 2-level bucket sort ----------------

__global__ __launch_bounds__(256) void bin_edges(const int* __restrict__ src,
                                                 const int* __restrict__ dst,
                                                 int* __restrict__ bcur,
                                                 int* __restrict__ binsrc,
                                                 int* __restrict__ bindst,
                                                 int CAP, int E) {
    __shared__ int lsrc[BCH], ldst[BCH];
    __shared__ int hist[128], base[128];
    int t = threadIdx.x;
    int e0 = blockIdx.x * BCH;
    if (t < 128) hist[t] = 0;
    __syncthreads();
    for (int k = t; k < BCH; k += 256) {
        int e = e0 + k;
        int d_ = -1, s_ = 0;
        if (e < E) {
            s_ = src[e];
            d_ = dst[e];
            atomicAdd(&hist[d_ >> 10], 1);
        }
        lsrc[k] = s_;
        ldst[k] = d_;
    }
    __syncthreads();
    if (t < 128) {
        int c = hist[t];
        base[t] = (c > 0) ? atomicAdd(&bcur[t], c) : 0;
        hist[t] = 0;
    }
    __syncthreads();
    for (int k = t; k < BCH; k += 256) {
        int d_ = ldst[k];
        if (d_ >= 0) {
            int b = d_ >> 10;
            int p = base[b] + atomicAdd(&hist[b], 1);
            binsrc[(size_t)b * CAP + p] = lsrc[k];
            bindst[(size_t)b * CAP + p] = d_;
        }
    }
}

__global__ __launch_bounds__(128) void scan_nb(const int* __restrict__ bcur,
                                               int* __restrict__ boff,
                                               int* __restrict__ csr,
                                               int NB, int N, int E) {
    __shared__ int tmp[128];
    int t = threadIdx.x;
    int v = (t < NB) ? bcur[t] : 0;
    tmp[t] = v;
    __syncthreads();
    for (int o = 1; o < 128; o <<= 1) {
        int x = (t >= o) ? tmp[t - o] : 0;
        __syncthreads();
        tmp[t] += x;
        __syncthreads();
    }
    if (t < NB) boff[t] = tmp[t] - v;
    if (t == 0) csr[N] = E;
}

__global__ __launch_bounds__(256) void build_csr(const int* __restrict__ binsrc,
                                                 const int* __restrict__ bindst,
                                                 const int* __restrict__ bcur,
                                                 const int* __restrict__ boff,
                                                 int* __restrict__ csr,
                                                 int* __restrict__ sorted,
                                                 float* __restrict__ dinv,
                                                 float* __restrict__ rdinv,
                                                 int CAP, int N) {
    __shared__ int hist[1024];
    __shared__ int part[256];
    int t = threadIdx.x;
    int b = blockIdx.x;
    int nb0 = b << 10;
    int cnt = bcur[b];
    int e0 = boff[b];
    const int* bs = binsrc + (size_t)b * CAP;
    const int* bd = bindst + (size_t)b * CAP;
    for (int k = t; k < 1024; k += 256) hist[k] = 0;
    __syncthreads();
    for (int k = t; k < cnt; k += 256) atomicAdd(&hist[bd[k] - nb0], 1);
    __syncthreads();
    int v0 = hist[4 * t], v1 = hist[4 * t + 1], v2 = hist[4 * t + 2], v3 = hist[4 * t + 3];
    part[t] = v0 + v1 + v2 + v3;
    __syncthreads();
    for (int o = 1; o < 256; o <<= 1) {
        int x = (t >= o) ? part[t - o] : 0;
        __syncthreads();
        part[t] += x;
        __syncthreads();
    }
    int run = (t > 0) ? part[t - 1] : 0;
    int pre[4];
    pre[0] = run;
    pre[1] = run + v0;
    pre[2] = run + v0 + v1;
    pre[3] = run + v0 + v1 + v2;
    int deg[4] = {v0, v1, v2, v3};
    __syncthreads();
    hist[4 * t + 0] = e0 + pre[0];
    hist[4 * t + 1] = e0 + pre[1];
    hist[4 * t + 2] = e0 + pre[2];
    hist[4 * t + 3] = e0 + pre[3];
#pragma unroll
    for (int j = 0; j < 4; j++) {
        int node = nb0 + 4 * t + j;
        if (node < N) {
            csr[node] = e0 + pre[j];
            float c = (float)deg[j] + 1.0f;
            dinv[node] = rsqrtf(c);
            rdinv[node] = sqrtf(c);
        }
    }
    __syncthreads();
    for (int k = t; k < cnt; k += 256) {
        int d_ = bd[k];
        int p = atomicAdd(&hist[d_ - nb0], 1);
        sorted[p] = bs[k];
    }
}

// ---------------- prep ----------------

__global__ __launch_bounds__(256) void prep_xd(const float* __restrict__ x,
                                               const float* __restrict__ dinv,
                                               ushort* __restrict__ actd, int N16) {
    int p = blockIdx.x * 256 + threadIdx.x;
    if (p >= N16) return;
    int n = p >> 4;
    float d = dinv[n];
    float4 v = reinterpret_cast<const float4*>(x)[p];
    ushort4 o;
    o.x = f2h(v.x * d);
    o.y = f2h(v.y * d);
    o.z = f2h(v.z * d);
    o.w = f2h(v.w * d);
    reinterpret_cast<ushort4*>(actd)[p] = o;
}

__global__ __launch_bounds__(256) void wprep(const float* __restrict__ W,
                                             ushort* __restrict__ wfrag) {
    int idx = blockIdx.x * 256 + threadIdx.x;
    if (idx >= 4096) return;
    int i = idx & 7;
    int lane = (idx >> 3) & 63;
    int hc = idx >> 9;
    int h = hc >> 2, c = hc & 3;
    int k = h * 32 + (lane >> 4) * 8 + i;
    int j = c * 16 + (lane & 15);
    wfrag[idx] = f2h(W[k * 64 + j]);
}

// finalize BN affine + u = C@W + W-fragment prep, one block
__global__ __launch_bounds__(256) void layer_prep(const float* __restrict__ ssum,
                                                  const float* __restrict__ sssq,
                                                  const float* __restrict__ gamma,
                                                  const float* __restrict__ beta,
                                                  const float* __restrict__ W,
                                                  float* __restrict__ A,
                                                  float* __restrict__ C,
                                                  float* __restrict__ u,
                                                  ushort* __restrict__ wfrag,
                                                  float invN) {
    __shared__ float As[64], Cs[64];
    int t = threadIdx.x;
    if (t < 64) {
        float m = ssum[t] * invN;
        float var = sssq[t] * invN - m * m;
        float rs = rsqrtf(var + 1e-4f);
        float a = rs * gamma[t];
        As[t] = a;
        A[t] = a;
        float c = fmaf(-m, a, beta[t]);
        Cs[t] = c;
        C[t] = c;
    }
    __syncthreads();
    if (t < 64) {
        float s = 0.f;
        for (int k = 0; k < 64; k++) s = fmaf(Cs[k], W[k * 64 + t], s);
        u[t] = s;
    }
    for (int idx = t; idx < 4096; idx += 256) {
        int i = idx & 7;
        int lane = (idx >> 3) & 63;
        int hc = idx >> 9;
        int h = hc >> 2, c = hc & 3;
        int k = h * 32 + (lane >> 4) * 8 + i;
        int j = c * 16 + (lane & 15);
        wfrag[idx] = f2h(W[k * 64 + j] * As[k]);
    }
}

__global__ __launch_bounds__(64) void finalize_aff(const float* __restrict__ ssum,
                                                   const float* __restrict__ sssq,
                                                   const float* __restrict__ gamma,
                                                   const float* __restrict__ beta,
                                                   float* __restrict__ A,
                                                   float* __restrict__ C, float invN) {
    int c = threadIdx.x;
    float m = ssum[c] * invN;
    float var = sssq[c] * invN - m * m;
    float rs = rsqrtf(var + 1e-4f);
    float a = rs * gamma[c];
    A[c] = a;
    C[c] = fmaf(-m, a, beta[c]);
}

// ---------------- aggregation (full-wave, scalar-addressed gathers) ----------------

// 128B rows: feature = lane (ushort). 1 node per wave, index broadcast via readlane.
__global__ __launch_bounds__(256) void agg_g(const ushort* __restrict__ actd,
                                             const int* __restrict__ ptr,
                                             const int* __restrict__ srcs,
                                             const float* __restrict__ dinv,
                                             const float* __restrict__ rdinv,
                                             ushort* __restrict__ zh,
                                             float* __restrict__ ssum,
                                             float* __restrict__ sssq,
                                             float* __restrict__ qout, int N, int E) {
    __shared__ float red[2][4][64];
    int lane = threadIdx.x & 63;
    int wv = threadIdx.x >> 6;
    int Em1 = E - 1;
    const bool do_stats = (ssum != nullptr);
    const bool do_q = (qout != nullptr);
    float ps = 0.f, pq = 0.f;
    for (int n = blockIdx.x * 4 + wv; n < N; n += gridDim.x * 4) {
        int s = ptr[n], e = ptr[n + 1];
        float self = h2f(actd[((size_t)n << 6) + lane]);
        float acc = self;
        float dn = dinv[n];
        if (do_stats) {
            float a = self * rdinv[n];
            ps += a;
            pq += a * a;
        }
        float qa = 0.f;
        int i = s;
        int idx8 = srcs[min(i + (lane & 7), Em1)];
        while (i + 8 <= e) {
            int ni = i + 8;
            int nidx = srcs[min(ni + (lane & 7), Em1)];
#pragma unroll
            for (int j = 0; j < 8; j++) {
                int u = __builtin_amdgcn_readlane(idx8, j);
                float f = h2f(actd[((size_t)u << 6) + lane]);
                acc += f;
                if (do_q) qa += dinv[u];
            }
            idx8 = nidx;
            i = ni;
        }
        if (i < e) {
#pragma unroll
            for (int j = 0; j < 8; j++) {
                int u = __builtin_amdgcn_readlane(idx8, j);
                float f = h2f(actd[((size_t)u << 6) + lane]);
                float w = (i + j < e) ? 1.0f : 0.0f;
                acc = fmaf(w, f, acc);
                if (do_q) qa = fmaf(w, dinv[u], qa);
            }
        }
        if (do_q && lane == 0) qout[n] = dn * (dn + qa);
        zh[((size_t)n << 6) + lane] = f2h(acc * dn);
    }
    if (do_stats) {
        red[0][wv][lane] = ps;
        red[1][wv][lane] = pq;
        __syncthreads();
        if (wv == 0) {
            float t0 = red[0][0][lane] + red[0][1][lane] + red[0][2][lane] + red[0][3][lane];
            float t1 = red[1][0][lane] + red[1][1][lane] + red[1][2][lane] + red[1][3][lane];
            atomicAdd(&ssum[lane], t0);
            atomicAdd(&sssq[lane], t1);
        }
    }
}

// 256B rows (att|str interleaved): features 2*lane, 2*lane+1 (uint).
__global__ __launch_bounds__(256) void agg_dual(const ushort* __restrict__ ab,
                                                const int* __restrict__ ptr,
                                                const int* __restrict__ srcs,
                                                const float* __restrict__ dinv,
                                                const float* __restrict__ rdinv,
                                                ushort* __restrict__ zab,
                                                float* __restrict__ ssA,
                                                float* __restrict__ sqA,
                                                float* __restrict__ ssS,
                                                float* __restrict__ sqS,
                                                int N, int E) {
    __shared__ float red[2][4][128];
    int lane = threadIdx.x & 63;
    int wv = threadIdx.x >> 6;
    int Em1 = E - 1;
    float2 ps = make_float2(0.f, 0.f), pq = make_float2(0.f, 0.f);
    for (int n = blockIdx.x * 4 + wv; n < N; n += gridDim.x * 4) {
        int s = ptr[n], e = ptr[n + 1];
        uint su = *reinterpret_cast<const uint*>(ab + ((size_t)n << 7) + (lane << 1));
        float2 acc = up2(su);
        {
            float r = rdinv[n];
            float ax = acc.x * r, ay = acc.y * r;
            ps.x += ax; ps.y += ay;
            pq.x += ax * ax; pq.y += ay * ay;
        }
        int i = s;
        int idx8 = srcs[min(i + (lane & 7), Em1)];
        while (i + 8 <= e) {
            int ni = i + 8;
            int nidx = srcs[min(ni + (lane & 7), Em1)];
#pragma unroll
            for (int j = 0; j < 8; j++) {
                int u = __builtin_amdgcn_readlane(idx8, j);
                uint v = *reinterpret_cast<const uint*>(ab + ((size_t)u << 7) + (lane << 1));
                float2 f = up2(v);
                acc.x += f.x;
                acc.y += f.y;
            }
            idx8 = nidx;
            i = ni;
        }
        if (i < e) {
#pragma unroll
            for (int j = 0; j < 8; j++) {
                int u = __builtin_amdgcn_readlane(idx8, j);
                uint v = *reinterpret_cast<const uint*>(ab + ((size_t)u << 7) + (lane << 1));
                float w = (i + j < e) ? 1.0f : 0.0f;
                float2 f = up2(v);
                acc.x = fmaf(w, f.x, acc.x);
                acc.y = fmaf(w, f.y, acc.y);
            }
        }
        float dn = dinv[n];
        uint pk = (uint)f2h(acc.x * dn) | ((uint)f2h(acc.y * dn) << 16);
        *reinterpret_cast<uint*>(zab + ((size_t)n << 7) + (lane << 1)) = pk;
    }
    red[0][wv][2 * lane + 0] = ps.x;
    red[0][wv][2 * lane + 1] = ps.y;
    red[1][wv][2 * lane + 0] = pq.x;
    red[1][wv][2 * lane + 1] = pq.y;
    __syncthreads();
    if (wv == 0) {
#pragma unroll
        for (int m0 = 0; m0 < 2; m0++) {
            int m = lane + m0 * 64;
            float t0 = red[0][0][m] + red[0][1][m] + red[0][2][m] + red[0][3][m];
            float t1 = red[1][0][m] + red[1][1][m] + red[1][2][m] + red[1][3][m];
            if (m < 64) {
                atomicAdd(&ssA[m], t0);
                atomicAdd(&sqA[m], t1);
            } else {
                atomicAdd(&ssS[m - 64], t0);
                atomicAdd(&sqS[m - 64], t1);
            }
        }
    }
}

// ---------------- MFMA GEMM ----------------
// OM: 0 = write fp16(act*dinv) to outh; 1 = stats only (s0=ssum, s1=sssq);
//     2 = apply affine (s0=A, s1=C) and write f32 to outf.
template <int MODE, bool HAS_AFF, int OM>
__global__ __launch_bounds__(256) void gemm_mfma(const ushort* __restrict__ zh, int is,
                                                 const ushort* __restrict__ wfrag,
                                                 const float* __restrict__ bias,
                                                 const float* __restrict__ u,
                                                 const float* __restrict__ q,
                                                 const float* __restrict__ dinv,
                                                 ushort* __restrict__ outh, int os,
                                                 float* __restrict__ outf,
                                                 float* __restrict__ s0,
                                                 float* __restrict__ s1, int N) {
    int tid = threadIdx.x;
    int lane = tid & 63;
    int wv = tid >> 6;
    int l15 = lane & 15;
    int lg = lane >> 4;
    int tb = blockIdx.x * 64;

    const ushort* zrow = zh + (size_t)(tb + wv * 16 + l15) * is + (lg << 3);
    f16x8 a0 = *reinterpret_cast<const f16x8*>(zrow);
    f16x8 a1 = *reinterpret_cast<const f16x8*>(zrow + 32);

    const f16x8* wf = reinterpret_cast<const f16x8*>(wfrag) + lane;

    f32x4 acc[4];
#pragma unroll
    for (int c = 0; c < 4; c++) {
        f32x4 t = {0.f, 0.f, 0.f, 0.f};
        t = __builtin_amdgcn_mfma_f32_16x16x32_f16(a0, wf[(0 * 4 + c) * 64], t, 0, 0, 0);
        t = __builtin_amdgcn_mfma_f32_16x16x32_f16(a1, wf[(1 * 4 + c) * 64], t, 0, 0, 0);
        acc[c] = t;
    }

    int rowbase = tb + wv * 16 + lg * 4;
    float qv[4], dv[4];
    bool vld[4];
#pragma unroll
    for (int r = 0; r < 4; r++) {
        int row = rowbase + r;
        vld[r] = row < N;
        qv[r] = (HAS_AFF && vld[r]) ? q[row] : 0.f;
        dv[r] = (OM == 0 && vld[r]) ? dinv[row] : 0.f;
    }
    float sa[4], sq[4];
#pragma unroll
    for (int c = 0; c < 4; c++) { sa[c] = 0.f; sq[c] = 0.f; }

#pragma unroll
    for (int c = 0; c < 4; c++) {
        int col = c * 16 + l15;
        float bcol = bias[col];
        float ucol = HAS_AFF ? u[col] : 0.f;
        float Acol = (OM == 2) ? s0[col] : 0.f;
        float Ccol = (OM == 2) ? s1[col] : 0.f;
#pragma unroll
        for (int r = 0; r < 4; r++) {
            if (!vld[r]) continue;
            float o = acc[c][r] + bcol;
            if (HAS_AFF) o = fmaf(qv[r], ucol, o);
            float a = (MODE == 0) ? sigmoidf_(o)
                                  : ((MODE == 1) ? o : sigmoidf_(0.5f * o));
            int row = rowbase + r;
            if (OM == 0) {
                outh[(size_t)row * os + col] = f2h(a * dv[r]);
            } else if (OM == 1) {
                sa[c] += a;
                sq[c] += a * a;
            } else {
                outf[((size_t)row << 6) + col] = fmaf(a, Acol, Ccol);
            }
        }
    }

    if (OM == 1) {
        __shared__ float red[2][4][4][16];
#pragma unroll
        for (int c = 0; c < 4; c++) {
            sa[c] += __shfl_xor(sa[c], 16);
            sa[c] += __shfl_xor(sa[c], 32);
            sq[c] += __shfl_xor(sq[c], 16);
            sq[c] += __shfl_xor(sq[c], 32);
        }
        if (lg == 0) {
#pragma unroll
            for (int c = 0; c < 4; c++) {
                red[0][wv][c][l15] = sa[c];
                red[1][wv][c][l15] = sq[c];
            }
        }
        __syncthreads();
        if (wv == 0) {
            int c = lane >> 4, l = lane & 15;
            float t0 = red[0][0][c][l] + red[0][1][c][l] + red[0][2][c][l] + red[0][3][c][l];
            float t1 = red[1][0][c][l] + red[1][1][c][l] + red[1][2][c][l] + red[1][3][c][l];
            atomicAdd(&s0[lane], t0);
            atomicAdd(&s1[lane], t1);
        }
    }
}

// fused att1+str1 GEMM: shared A-frags, two weight sets, writes interleaved hAB row.
__global__ __launch_bounds__(256) void gemm_dual(const ushort* __restrict__ zh,
                                                 const ushort* __restrict__ wfA,
                                                 const ushort* __restrict__ wfS,
                                                 const float* __restrict__ bA,
                                                 const float* __restrict__ bS,
                                                 const float* __restrict__ uA,
                                                 const float* __restrict__ uS,
                                                 const float* __restrict__ q,
                                                 const float* __restrict__ dinv,
                                                 ushort* __restrict__ outAB, int N) {
    int tid = threadIdx.x;
    int lane = tid & 63;
    int wv = tid >> 6;
    int l15 = lane & 15;
    int lg = lane >> 4;
    int tb = blockIdx.x * 64;

    const ushort* zrow = zh + ((size_t)(tb + wv * 16 + l15) << 6) + (lg << 3);
    f16x8 a0 = *reinterpret_cast<const f16x8*>(zrow);
    f16x8 a1 = *reinterpret_cast<const f16x8*>(zrow + 32);

    const f16x8* wa = reinterpret_cast<const f16x8*>(wfA) + lane;
    const f16x8* wsp = reinterpret_cast<const f16x8*>(wfS) + lane;

    f32x4 accA[4], accS[4];
#pragma unroll
    for (int c = 0; c < 4; c++) {
        f32x4 t = {0.f, 0.f, 0.f, 0.f};
        t = __builtin_amdgcn_mfma_f32_16x16x32_f16(a0, wa[(0 * 4 + c) * 64], t, 0, 0, 0);
        t = __builtin_amdgcn_mfma_f32_16x16x32_f16(a1, wa[(1 * 4 + c) * 64], t, 0, 0, 0);
        accA[c] = t;
        f32x4 t2 = {0.f, 0.f, 0.f, 0.f};
        t2 = __builtin_amdgcn_mfma_f32_16x16x32_f16(a0, wsp[(0 * 4 + c) * 64], t2, 0, 0, 0);
        t2 = __builtin_amdgcn_mfma_f32_16x16x32_f16(a1, wsp[(1 * 4 + c) * 64], t2, 0, 0, 0);
        accS[c] = t2;
    }

    int rowbase = tb + wv * 16 + lg * 4;
    float qv[4], dv[4];
    bool vld[4];
#pragma unroll
    for (int r = 0; r < 4; r++) {
        int row = rowbase + r;
        vld[r] = row < N;
        qv[r] = vld[r] ? q[row] : 0.f;
        dv[r] = vld[r] ? dinv[row] : 0.f;
    }
#pragma unroll
    for (int c = 0; c < 4; c++) {
        int col = c * 16 + l15;
        float bcA = bA[col], ucA = uA[col];
        float bcS = bS[col], ucS = uS[col];
#pragma unroll
        for (int r = 0; r < 4; r++) {
            if (!vld[r]) continue;
            int row = rowbase + r;
            float oA = fmaf(qv[r], ucA, accA[c][r] + bcA);
            float oS = fmaf(qv[r], ucS, accS[c][r] + bcS);
            float aA = sigmoidf_(oA);
            float aS = sigmoidf_(oS);
            outAB[((size_t)row << 7) + col] = f2h(aA * dv[r]);
            outAB[((size_t)row << 7) + 64 + col] = f2h(aS * dv[r]);
        }
    }
}

__global__ __launch_bounds__(256) void bn_apply_h(const ushort* __restrict__ actd,
                                                  const float* __restrict__ rdinv,
                                                  const float* __restrict__ A,
                                                  const float* __restrict__ C,
                                                  float* __restrict__ out, int N16) {
    int p = blockIdx.x * 256 + threadIdx.x;
    if (p >= N16) return;
    int n = p >> 4;
    int cb = (p & 15) * 4;
    float r = rdinv[n];
    ushort4 v = reinterpret_cast<const ushort4*>(actd)[p];
    float4 o;
    o.x = fmaf(h2f(v.x) * r, A[cb + 0], C[cb + 0]);
    o.y = fmaf(h2f(v.y) * r, A[cb + 1], C[cb + 1]);
    o.z = fmaf(h2f(v.z) * r, A[cb + 2], C[cb + 2]);
    o.w = fmaf(h2f(v.w) * r, A[cb + 3], C[cb + 3]);
    reinterpret_cast<float4*>(out)[p] = o;
}

// ---------------- launch ----------------

extern "C" void kernel_launch(void* const* d_in, const int* in_sizes, int n_in,
                              void* d_out, int out_size, void* d_ws, size_t ws_size,
                              hipStream_t stream) {
    const int N = in_sizes[0] / D;
    const int E = in_sizes[1] / 2;

    const float* x = (const float*)d_in[0];
    const int* ei = (const int*)d_in[1];
    const int* src_in = ei;
    const int* dst_in = ei + E;
    const float* encW = (const float*)d_in[3];
    const float* encb = (const float*)d_in[4];
    const float* encg = (const float*)d_in[5];
    const float* encbe = (const float*)d_in[6];
    const float* attW = (const float*)d_in[7];
    const float* attb = (const float*)d_in[8];
    const float* attg = (const float*)d_in[9];
    const float* attbe = (const float*)d_in[10];
    const float* strW = (const float*)d_in[11];
    const float* strb = (const float*)d_in[12];
    const float* strg = (const float*)d_in[13];
    const float* strbe = (const float*)d_in[14];

    const int NB = (N + 1023) >> 10;
    int CAP = (E + NB - 1) / NB;
    CAP = CAP + CAP / 8 + 256;
    CAP = (CAP + 255) & ~255;

    char* ws = (char*)d_ws;
    size_t off = 0;
    auto alloc = [&](size_t bytes) -> char* {
        char* p = ws + off;
        off += (bytes + 255) & ~(size_t)255;
        return p;
    };
    int* csr = (int*)alloc((size_t)(N + 1) * 4);
    int* bcur = (int*)alloc(128 * 4);
    int* boff = (int*)alloc(128 * 4);
    float* dinv = (float*)alloc((size_t)N * 4);
    float* rdinv = (float*)alloc((size_t)N * 4);
    float* q = (float*)alloc((size_t)N * 4);
    float* stats = (float*)alloc(6 * 128 * 4);
    float* aff = (float*)alloc(6 * 128 * 4);
    float* ubuf = (float*)alloc(6 * 64 * 4);
    ushort* wf = (ushort*)alloc(6 * 4096 * 2);
    int* sorted = (int*)alloc((size_t)E * 4);
    ushort* zh = (ushort*)alloc((size_t)(N + 64) * 64 * 2);
    size_t binbytes = 2 * (size_t)NB * CAP * 4;
    size_t zabbytes = (size_t)(N + 64) * 128 * 2;
    char* region = alloc(binbytes > zabbytes ? binbytes : zabbytes);
    int* binsrc = (int*)region;
    int* bindst = binsrc + (size_t)NB * CAP;
    ushort* zab = (ushort*)region;
    ushort* hA = (ushort*)alloc((size_t)N * 64 * 2);
    ushort* hB = (ushort*)alloc((size_t)N * 64 * 2);
    ushort* hAB = (ushort*)alloc((size_t)(N + 64) * 128 * 2);

    float* out_str = (float*)d_out;
    float* out_att = out_str + (size_t)N * D;
    float* out_enc = out_att + (size_t)N * D;

    hipMemsetAsync(bcur, 0, 128 * 4, stream);
    hipMemsetAsync(stats, 0, 6 * 128 * 4, stream);

    int N16 = N * 16;
    int g16 = (N16 + 255) / 256;
    int gT = (N + 63) / 64;
    float invN = 1.0f / (float)N;

    float* A0 = aff + 0 * 128; float* C0 = A0 + 64;
    float* A1 = aff + 1 * 128; float* C1 = A1 + 64;
    float* A2 = aff + 2 * 128; float* C2 = A2 + 64;
    float* A3 = aff + 3 * 128; float* C3 = A3 + 64;
    float* A4 = aff + 4 * 128; float* C4 = A4 + 64;
    float* A5 = aff + 5 * 128; float* C5 = A5 + 64;
    ushort* wf0 = wf + 0 * 4096;
    ushort* wf1 = wf + 1 * 4096;
    ushort* wf2 = wf + 2 * 4096;
    ushort* wf3 = wf + 3 * 4096;
    ushort* wf4 = wf + 4 * 4096;
    ushort* wf5 = wf + 5 * 4096;

    // ---- CSR build ----
    bin_edges<<<(E + BCH - 1) / BCH, 256, 0, stream>>>(src_in, dst_in, bcur,
                                                       binsrc, bindst, CAP, E);
    scan_nb<<<1, 128, 0, stream>>>(bcur, boff, csr, NB, N, E);
    build_csr<<<NB, 256, 0, stream>>>(binsrc, bindst, bcur, boff, csr, sorted,
                                      dinv, rdinv, CAP, N);

    // ---- encoder layer 1 (q fused into first gather) ----
    prep_xd<<<g16, 256, 0, stream>>>(x, dinv, hA, N16);
    wprep<<<16, 256, 0, stream>>>(encW, wf0);
    agg_g<<<2048, 256, 0, stream>>>(hA, csr, sorted, dinv, rdinv, zh,
                                    nullptr, nullptr, q, N, E);
    gemm_mfma<0, false, 0><<<gT, 256, 0, stream>>>(zh, 64, wf0, encb, nullptr,
                                                   q, dinv, hB, 64, nullptr,
                                                   nullptr, nullptr, N);
    // ---- encoder layer 2 ----
    agg_g<<<2048, 256, 0, stream>>>(hB, csr, sorted, dinv, rdinv, zh,
                                    stats + 0, stats + 64, nullptr, N, E);
    layer_prep<<<1, 256, 0, stream>>>(stats + 0, stats + 64, encg, encbe,
                                      encW + 4096, A0, C0, ubuf + 0, wf1, invN);
    gemm_mfma<0, true, 0><<<gT, 256, 0, stream>>>(zh, 64, wf1, encb + 64, ubuf + 0,
                                                  q, dinv, hA, 64, nullptr,
                                                  nullptr, nullptr, N);
    // ---- z2 = Agg(x_enc act); enc2 stats ----
    agg_g<<<2048, 256, 0, stream>>>(hA, csr, sorted, dinv, rdinv, zh,
                                    stats + 128, stats + 192, nullptr, N, E);
    layer_prep<<<1, 256, 0, stream>>>(stats + 128, stats + 192, encg + 64,
                                      encbe + 64, attW, A1, C1, ubuf + 64, wf2, invN);
    layer_prep<<<1, 256, 0, stream>>>(stats + 128, stats + 192, encg + 64,
                                      encbe + 64, strW, A1, C1, ubuf + 128, wf3, invN);
    bn_apply_h<<<g16, 256, 0, stream>>>(hA, rdinv, A1, C1, out_enc, N16);
    gemm_dual<<<gT, 256, 0, stream>>>(zh, wf2, wf3, attb, strb, ubuf + 64,
                                      ubuf + 128, q, dinv, hAB, N);
    // ---- fused att1|str1 gather (+ both stats) ----
    agg_dual<<<2048, 256, 0, stream>>>(hAB, csr, sorted, dinv, rdinv, zab,
                                       stats + 256, stats + 320,
                                       stats + 512, stats + 576, N, E);
    // ---- attribute layer 2 (stats-only GEMM -> finalize -> apply GEMM) ----
    layer_prep<<<1, 256, 0, stream>>>(stats + 256, stats + 320, attg, attbe,
                                      attW + 4096, A2, C2, ubuf + 192, wf4, invN);
    gemm_mfma<1, true, 1><<<gT, 256, 0, stream>>>(zab, 128, wf4, attb + 64,
                                                  ubuf + 192, q, dinv, nullptr, 0,
                                                  nullptr, stats + 384, stats + 448, N);
    finalize_aff<<<1, 64, 0, stream>>>(stats + 384, stats + 448, attg + 64,
                                       attbe + 64, A3, C3, invN);
    gemm_mfma<1, true, 2><<<gT, 256, 0, stream>>>(zab, 128, wf4, attb + 64,
                                                  ubuf + 192, q, dinv, nullptr, 0,
                                                  out_att, A3, C3, N);
    // ---- structure layer 2 ----
    layer_prep<<<1, 256, 0, stream>>>(stats + 512, stats + 576, strg, strbe,
                                      strW + 4096, A4, C4, ubuf + 320, wf5, invN);
    gemm_mfma<2, true, 1><<<gT, 256, 0, stream>>>(zab + 64, 128, wf5, strb + 64,
                                                  ubuf + 320, q, dinv, nullptr, 0,
                                                  nullptr, stats + 640, stats + 704, N);
    finalize_aff<<<1, 64, 0, stream>>>(stats + 640, stats + 704, strg + 64,
                                       strbe + 64, A5, C5, invN);
    gemm_mfma<2, true, 2><<<gT, 256, 0, stream>>>(zab + 64, 128, wf5, strb + 64,
                                                  ubuf + 320, q, dinv, nullptr, 0,
                                                  out_str, A5, C5, N);
}

// Round 9
// 602.813 us; speedup vs baseline: 6.1865x; 1.0034x over previous
//
#include <hip/hip_runtime.h>

#define D 64
#define BCH 4096

typedef __attribute__((ext_vector_type(8))) _Float16 f16x8;
typedef __attribute__((ext_vector_type(4))) float f32x4;

__device__ __forceinline__ float sigmoidf_(float x) {
    return 1.0f / (1.0f + __expf(-x));
}
__device__ __forceinline__ float h2f(ushort u) {
    _Float16 h;
    __builtin_memcpy(&h, &u, 2);
    return (float)h;
}
__device__ __forceinline__ ushort f2h(float f) {
    _Float16 h = (_Float16)f;
    ushort u;
    __builtin_memcpy(&u, &h, 2);
    return u;
}
__device__ __forceinline__ float2 up2(uint v) {
    float2 r;
    r.x = h2f((ushort)(v & 0xffffu));
    r.y = h2f((ushort)(v >> 16));
    return r;
}

// ---------------- CSR build: 2-level bucket sort, packed (src<<10 | dstlocal) ----------------

__global__ __launch_bounds__(256) void bin_edges(const int* __restrict__ src,
                                                 const int* __restrict__ dst,
                                                 int* __restrict__ bcur,
                                                 uint* __restrict__ bins,
                                                 int CAP, int E) {
    __shared__ uint lp[BCH];
    __shared__ unsigned char lb[BCH];
    __shared__ int hist[128], base[128];
    int t = threadIdx.x;
    int e0 = blockIdx.x * BCH;
    if (t < 128) hist[t] = 0;
    __syncthreads();
    for (int k = t; k < BCH; k += 256) {
        int e = e0 + k;
        uint p = 0xFFFFFFFFu;
        int b = 0;
        if (e < E) {
            int s_ = src[e];
            int d_ = dst[e];
            b = d_ >> 10;
            atomicAdd(&hist[b], 1);
            p = ((uint)s_ << 10) | (uint)(d_ & 1023);
        }
        lp[k] = p;
        lb[k] = (unsigned char)b;
    }
    __syncthreads();
    if (t < 128) {
        int c = hist[t];
        base[t] = (c > 0) ? atomicAdd(&bcur[t], c) : 0;
        hist[t] = 0;
    }
    __syncthreads();
    for (int k = t; k < BCH; k += 256) {
        uint p = lp[k];
        if (p != 0xFFFFFFFFu) {
            int b = lb[k];
            int pos = base[b] + atomicAdd(&hist[b], 1);
            bins[(size_t)b * CAP + pos] = p;
        }
    }
}

__global__ __launch_bounds__(128) void scan_nb(const int* __restrict__ bcur,
                                               int* __restrict__ boff,
                                               int* __restrict__ csr,
                                               int NB, int N, int E) {
    __shared__ int tmp[128];
    int t = threadIdx.x;
    int v = (t < NB) ? bcur[t] : 0;
    tmp[t] = v;
    __syncthreads();
    for (int o = 1; o < 128; o <<= 1) {
        int x = (t >= o) ? tmp[t - o] : 0;
        __syncthreads();
        tmp[t] += x;
        __syncthreads();
    }
    if (t < NB) boff[t] = tmp[t] - v;
    if (t == 0) csr[N] = E;
}

__global__ __launch_bounds__(256) void build_csr(const uint* __restrict__ bins,
                                                 const int* __restrict__ bcur,
                                                 const int* __restrict__ boff,
                                                 int* __restrict__ csr,
                                                 int* __restrict__ sorted,
                                                 float* __restrict__ dinv,
                                                 float* __restrict__ rdinv,
                                                 int CAP, int N) {
    __shared__ int hist[1024];
    __shared__ int part[256];
    int t = threadIdx.x;
    int b = blockIdx.x;
    int nb0 = b << 10;
    int cnt = bcur[b];
    int e0 = boff[b];
    const uint* bp = bins + (size_t)b * CAP;
    for (int k = t; k < 1024; k += 256) hist[k] = 0;
    __syncthreads();
    for (int k = t; k < cnt; k += 256) atomicAdd(&hist[bp[k] & 1023u], 1);
    __syncthreads();
    int v0 = hist[4 * t], v1 = hist[4 * t + 1], v2 = hist[4 * t + 2], v3 = hist[4 * t + 3];
    part[t] = v0 + v1 + v2 + v3;
    __syncthreads();
    for (int o = 1; o < 256; o <<= 1) {
        int x = (t >= o) ? part[t - o] : 0;
        __syncthreads();
        part[t] += x;
        __syncthreads();
    }
    int run = (t > 0) ? part[t - 1] : 0;
    int pre[4];
    pre[0] = run;
    pre[1] = run + v0;
    pre[2] = run + v0 + v1;
    pre[3] = run + v0 + v1 + v2;
    int deg[4] = {v0, v1, v2, v3};
    __syncthreads();
    hist[4 * t + 0] = e0 + pre[0];
    hist[4 * t + 1] = e0 + pre[1];
    hist[4 * t + 2] = e0 + pre[2];
    hist[4 * t + 3] = e0 + pre[3];
#pragma unroll
    for (int j = 0; j < 4; j++) {
        int node = nb0 + 4 * t + j;
        if (node < N) {
            csr[node] = e0 + pre[j];
            float c = (float)deg[j] + 1.0f;
            dinv[node] = rsqrtf(c);
            rdinv[node] = sqrtf(c);
        }
    }
    __syncthreads();
    for (int k = t; k < cnt; k += 256) {
        uint p = bp[k];
        int pos = atomicAdd(&hist[p & 1023u], 1);
        sorted[pos] = (int)(p >> 10);
    }
}

// ---------------- prep ----------------

__global__ __launch_bounds__(256) void prep_xd(const float* __restrict__ x,
                                               const float* __restrict__ dinv,
                                               ushort* __restrict__ actd, int N16) {
    int p = blockIdx.x * 256 + threadIdx.x;
    if (p >= N16) return;
    int n = p >> 4;
    float d = dinv[n];
    float4 v = reinterpret_cast<const float4*>(x)[p];
    ushort4 o;
    o.x = f2h(v.x * d);
    o.y = f2h(v.y * d);
    o.z = f2h(v.z * d);
    o.w = f2h(v.w * d);
    reinterpret_cast<ushort4*>(actd)[p] = o;
}

__global__ __launch_bounds__(256) void wprep(const float* __restrict__ W,
                                             ushort* __restrict__ wfrag) {
    int idx = blockIdx.x * 256 + threadIdx.x;
    if (idx >= 4096) return;
    int i = idx & 7;
    int lane = (idx >> 3) & 63;
    int hc = idx >> 9;
    int h = hc >> 2, c = hc & 3;
    int k = h * 32 + (lane >> 4) * 8 + i;
    int j = c * 16 + (lane & 15);
    wfrag[idx] = f2h(W[k * 64 + j]);
}

__global__ __launch_bounds__(256) void layer_prep(const float* __restrict__ ssum,
                                                  const float* __restrict__ sssq,
                                                  const float* __restrict__ gamma,
                                                  const float* __restrict__ beta,
                                                  const float* __restrict__ W,
                                                  float* __restrict__ A,
                                                  float* __restrict__ C,
                                                  float* __restrict__ u,
                                                  ushort* __restrict__ wfrag,
                                                  float invN) {
    __shared__ float As[64], Cs[64];
    int t = threadIdx.x;
    if (t < 64) {
        float m = ssum[t] * invN;
        float var = sssq[t] * invN - m * m;
        float rs = rsqrtf(var + 1e-4f);
        float a = rs * gamma[t];
        As[t] = a;
        A[t] = a;
        float c = fmaf(-m, a, beta[t]);
        Cs[t] = c;
        C[t] = c;
    }
    __syncthreads();
    if (t < 64) {
        float s = 0.f;
        for (int k = 0; k < 64; k++) s = fmaf(Cs[k], W[k * 64 + t], s);
        u[t] = s;
    }
    for (int idx = t; idx < 4096; idx += 256) {
        int i = idx & 7;
        int lane = (idx >> 3) & 63;
        int hc = idx >> 9;
        int h = hc >> 2, c = hc & 3;
        int k = h * 32 + (lane >> 4) * 8 + i;
        int j = c * 16 + (lane & 15);
        wfrag[idx] = f2h(W[k * 64 + j] * As[k]);
    }
}

__global__ __launch_bounds__(64) void finalize_aff(const float* __restrict__ ssum,
                                                   const float* __restrict__ sssq,
                                                   const float* __restrict__ gamma,
                                                   const float* __restrict__ beta,
                                                   float* __restrict__ A,
                                                   float* __restrict__ C, float invN) {
    int c = threadIdx.x;
    float m = ssum[c] * invN;
    float var = sssq[c] * invN - m * m;
    float rs = rsqrtf(var + 1e-4f);
    float a = rs * gamma[c];
    A[c] = a;
    C[c] = fmaf(-m, a, beta[c]);
}

// ---------------- aggregation: two independent node streams per wave ----------------

// 128B rows, feature = lane (ushort loads).
__global__ __launch_bounds__(256) void agg_g(const ushort* __restrict__ actd,
                                             const int* __restrict__ ptr,
                                             const int* __restrict__ srcs,
                                             const float* __restrict__ dinv,
                                             const float* __restrict__ rdinv,
                                             ushort* __restrict__ zh,
                                             float* __restrict__ ssum,
                                             float* __restrict__ sssq,
                                             float* __restrict__ qout, int N, int E) {
    __shared__ float red[2][4][64];
    int lane = threadIdx.x & 63;
    int wv = threadIdx.x >> 6;
    int l7 = lane & 7;
    int Em1 = E - 1;
    const bool do_stats = (ssum != nullptr);
    const bool do_q = (qout != nullptr);
    float ps = 0.f, pq = 0.f;
    int Nh = (N + 1) >> 1;
    for (int n0 = blockIdx.x * 4 + wv; n0 < Nh; n0 += gridDim.x * 4) {
        int nA = n0;
        int nB = n0 + Nh;
        bool hasB = nB < N;
        int sA = ptr[nA], eA = ptr[nA + 1];
        int sB = 0, eB = 0;
        if (hasB) { sB = ptr[nB]; eB = ptr[nB + 1]; }
        float selfA = h2f(actd[((size_t)nA << 6) + lane]);
        float accA = selfA;
        float dnA = dinv[nA];
        float accB = 0.f, dnB = 0.f;
        if (hasB) {
            float selfB = h2f(actd[((size_t)nB << 6) + lane]);
            accB = selfB;
            dnB = dinv[nB];
            if (do_stats) {
                float rb = rdinv[nB];
                float b = selfB * rb;
                ps += b;
                pq += b * b;
            }
        }
        if (do_stats) {
            float ra = rdinv[nA];
            float a = selfA * ra;
            ps += a;
            pq += a * a;
        }
        float qaA = 0.f, qaB = 0.f;
        int iA = sA, iB = sB;
        int idxA = srcs[min(iA + l7, Em1)];
        int idxB = hasB ? srcs[min(iB + l7, Em1)] : 0;
        while (iA + 8 <= eA || iB + 8 <= eB) {
            bool gA = iA + 8 <= eA;
            bool gB = iB + 8 <= eB;
            ushort ua[8], ub[8];
            if (gA) {
#pragma unroll
                for (int j = 0; j < 8; j++) {
                    int u = __builtin_amdgcn_readlane(idxA, j);
                    ua[j] = actd[((size_t)u << 6) + lane];
                    if (do_q) qaA += dinv[u];
                }
            }
            if (gB) {
#pragma unroll
                for (int j = 0; j < 8; j++) {
                    int u = __builtin_amdgcn_readlane(idxB, j);
                    ub[j] = actd[((size_t)u << 6) + lane];
                    if (do_q) qaB += dinv[u];
                }
            }
            int idxA2 = idxA, idxB2 = idxB;
            if (gA) idxA2 = srcs[min(iA + 8 + l7, Em1)];
            if (gB) idxB2 = srcs[min(iB + 8 + l7, Em1)];
            if (gA) {
                accA += ((h2f(ua[0]) + h2f(ua[1])) + (h2f(ua[2]) + h2f(ua[3]))) +
                        ((h2f(ua[4]) + h2f(ua[5])) + (h2f(ua[6]) + h2f(ua[7])));
                iA += 8;
                idxA = idxA2;
            }
            if (gB) {
                accB += ((h2f(ub[0]) + h2f(ub[1])) + (h2f(ub[2]) + h2f(ub[3]))) +
                        ((h2f(ub[4]) + h2f(ub[5])) + (h2f(ub[6]) + h2f(ub[7])));
                iB += 8;
                idxB = idxB2;
            }
        }
        if (iA < eA) {
#pragma unroll
            for (int j = 0; j < 8; j++) {
                int u = __builtin_amdgcn_readlane(idxA, j);
                float w = (iA + j < eA) ? 1.0f : 0.0f;
                float f = h2f(actd[((size_t)u << 6) + lane]);
                accA = fmaf(w, f, accA);
                if (do_q) qaA = fmaf(w, dinv[u], qaA);
            }
        }
        if (hasB && iB < eB) {
#pragma unroll
            for (int j = 0; j < 8; j++) {
                int u = __builtin_amdgcn_readlane(idxB, j);
                float w = (iB + j < eB) ? 1.0f : 0.0f;
                float f = h2f(actd[((size_t)u << 6) + lane]);
                accB = fmaf(w, f, accB);
                if (do_q) qaB = fmaf(w, dinv[u], qaB);
            }
        }
        if (do_q && lane == 0) {
            qout[nA] = dnA * (dnA + qaA);
            if (hasB) qout[nB] = dnB * (dnB + qaB);
        }
        zh[((size_t)nA << 6) + lane] = f2h(accA * dnA);
        if (hasB) zh[((size_t)nB << 6) + lane] = f2h(accB * dnB);
    }
    if (do_stats) {
        red[0][wv][lane] = ps;
        red[1][wv][lane] = pq;
        __syncthreads();
        if (wv == 0) {
            float t0 = red[0][0][lane] + red[0][1][lane] + red[0][2][lane] + red[0][3][lane];
            float t1 = red[1][0][lane] + red[1][1][lane] + red[1][2][lane] + red[1][3][lane];
            atomicAdd(&ssum[lane], t0);
            atomicAdd(&sssq[lane], t1);
        }
    }
}

// 256B rows (att|str interleaved), features 2*lane, 2*lane+1 (uint loads).
__global__ __launch_bounds__(256) void agg_dual(const ushort* __restrict__ ab,
                                                const int* __restrict__ ptr,
                                                const int* __restrict__ srcs,
                                                const float* __restrict__ dinv,
                                                const float* __restrict__ rdinv,
                                                ushort* __restrict__ zab,
                                                float* __restrict__ ssA,
                                                float* __restrict__ sqA,
                                                float* __restrict__ ssS,
                                                float* __restrict__ sqS,
                                                int N, int E) {
    __shared__ float red[2][4][128];
    int lane = threadIdx.x & 63;
    int wv = threadIdx.x >> 6;
    int l7 = lane & 7;
    int Em1 = E - 1;
    float2 ps = make_float2(0.f, 0.f), pq = make_float2(0.f, 0.f);
    int Nh = (N + 1) >> 1;
    for (int n0 = blockIdx.x * 4 + wv; n0 < Nh; n0 += gridDim.x * 4) {
        int nA = n0;
        int nB = n0 + Nh;
        bool hasB = nB < N;
        int sA = ptr[nA], eA = ptr[nA + 1];
        int sB = 0, eB = 0;
        if (hasB) { sB = ptr[nB]; eB = ptr[nB + 1]; }
        uint suA = *reinterpret_cast<const uint*>(ab + ((size_t)nA << 7) + (lane << 1));
        float2 accA = up2(suA);
        float dnA = dinv[nA];
        {
            float r = rdinv[nA];
            float ax = accA.x * r, ay = accA.y * r;
            ps.x += ax; ps.y += ay;
            pq.x += ax * ax; pq.y += ay * ay;
        }
        float2 accB = make_float2(0.f, 0.f);
        float dnB = 0.f;
        if (hasB) {
            uint suB = *reinterpret_cast<const uint*>(ab + ((size_t)nB << 7) + (lane << 1));
            accB = up2(suB);
            dnB = dinv[nB];
            float r = rdinv[nB];
            float ax = accB.x * r, ay = accB.y * r;
            ps.x += ax; ps.y += ay;
            pq.x += ax * ax; pq.y += ay * ay;
        }
        int iA = sA, iB = sB;
        int idxA = srcs[min(iA + l7, Em1)];
        int idxB = hasB ? srcs[min(iB + l7, Em1)] : 0;
        while (iA + 8 <= eA || iB + 8 <= eB) {
            bool gA = iA + 8 <= eA;
            bool gB = iB + 8 <= eB;
            uint va[8], vb[8];
            if (gA) {
#pragma unroll
                for (int j = 0; j < 8; j++) {
                    int u = __builtin_amdgcn_readlane(idxA, j);
                    va[j] = *reinterpret_cast<const uint*>(ab + ((size_t)u << 7) + (lane << 1));
                }
            }
            if (gB) {
#pragma unroll
                for (int j = 0; j < 8; j++) {
                    int u = __builtin_amdgcn_readlane(idxB, j);
                    vb[j] = *reinterpret_cast<const uint*>(ab + ((size_t)u << 7) + (lane << 1));
                }
            }
            int idxA2 = idxA, idxB2 = idxB;
            if (gA) idxA2 = srcs[min(iA + 8 + l7, Em1)];
            if (gB) idxB2 = srcs[min(iB + 8 + l7, Em1)];
            if (gA) {
#pragma unroll
                for (int j = 0; j < 8; j++) {
                    float2 f = up2(va[j]);
                    accA.x += f.x;
                    accA.y += f.y;
                }
                iA += 8;
                idxA = idxA2;
            }
            if (gB) {
#pragma unroll
                for (int j = 0; j < 8; j++) {
                    float2 f = up2(vb[j]);
                    accB.x += f.x;
                    accB.y += f.y;
                }
                iB += 8;
                idxB = idxB2;
            }
        }
        if (iA < eA) {
#pragma unroll
            for (int j = 0; j < 8; j++) {
                int u = __builtin_amdgcn_readlane(idxA, j);
                uint v = *reinterpret_cast<const uint*>(ab + ((size_t)u << 7) + (lane << 1));
                float w = (iA + j < eA) ? 1.0f : 0.0f;
                float2 f = up2(v);
                accA.x = fmaf(w, f.x, accA.x);
                accA.y = fmaf(w, f.y, accA.y);
            }
        }
        if (hasB && iB < eB) {
#pragma unroll
            for (int j = 0; j < 8; j++) {
                int u = __builtin_amdgcn_readlane(idxB, j);
                uint v = *reinterpret_cast<const uint*>(ab + ((size_t)u << 7) + (lane << 1));
                float w = (iB + j < eB) ? 1.0f : 0.0f;
                float2 f = up2(v);
                accB.x = fmaf(w, f.x, accB.x);
                accB.y = fmaf(w, f.y, accB.y);
            }
        }
        uint pkA = (uint)f2h(accA.x * dnA) | ((uint)f2h(accA.y * dnA) << 16);
        *reinterpret_cast<uint*>(zab + ((size_t)nA << 7) + (lane << 1)) = pkA;
        if (hasB) {
            uint pkB = (uint)f2h(accB.x * dnB) | ((uint)f2h(accB.y * dnB) << 16);
            *reinterpret_cast<uint*>(zab + ((size_t)nB << 7) + (lane << 1)) = pkB;
        }
    }
    red[0][wv][2 * lane + 0] = ps.x;
    red[0][wv][2 * lane + 1] = ps.y;
    red[1][wv][2 * lane + 0] = pq.x;
    red[1][wv][2 * lane + 1] = pq.y;
    __syncthreads();
    if (wv == 0) {
#pragma unroll
        for (int m0 = 0; m0 < 2; m0++) {
            int m = lane + m0 * 64;
            float t0 = red[0][0][m] + red[0][1][m] + red[0][2][m] + red[0][3][m];
            float t1 = red[1][0][m] + red[1][1][m] + red[1][2][m] + red[1][3][m];
            if (m < 64) {
                atomicAdd(&ssA[m], t0);
                atomicAdd(&sqA[m], t1);
            } else {
                atomicAdd(&ssS[m - 64], t0);
                atomicAdd(&sqS[m - 64], t1);
            }
        }
    }
}

// ---------------- MFMA GEMM ----------------
// OM: 0 = write fp16(act*dinv); 1 = stats only (s0=ssum, s1=sssq);
//     2 = apply affine (s0=A, s1=C), write f32.
template <int MODE, bool HAS_AFF, int OM>
__global__ __launch_bounds__(256) void gemm_mfma(const ushort* __restrict__ zh, int is,
                                                 const ushort* __restrict__ wfrag,
                                                 const float* __restrict__ bias,
                                                 const float* __restrict__ u,
                                                 const float* __restrict__ q,
                                                 const float* __restrict__ dinv,
                                                 ushort* __restrict__ outh, int os,
                                                 float* __restrict__ outf,
                                                 float* __restrict__ s0,
                                                 float* __restrict__ s1, int N) {
    int tid = threadIdx.x;
    int lane = tid & 63;
    int wv = tid >> 6;
    int l15 = lane & 15;
    int lg = lane >> 4;
    int tb = blockIdx.x * 64;

    const ushort* zrow = zh + (size_t)(tb + wv * 16 + l15) * is + (lg << 3);
    f16x8 a0 = *reinterpret_cast<const f16x8*>(zrow);
    f16x8 a1 = *reinterpret_cast<const f16x8*>(zrow + 32);

    const f16x8* wf = reinterpret_cast<const f16x8*>(wfrag) + lane;

    f32x4 acc[4];
#pragma unroll
    for (int c = 0; c < 4; c++) {
        f32x4 t = {0.f, 0.f, 0.f, 0.f};
        t = __builtin_amdgcn_mfma_f32_16x16x32_f16(a0, wf[(0 * 4 + c) * 64], t, 0, 0, 0);
        t = __builtin_amdgcn_mfma_f32_16x16x32_f16(a1, wf[(1 * 4 + c) * 64], t, 0, 0, 0);
        acc[c] = t;
    }

    int rowbase = tb + wv * 16 + lg * 4;
    float qv[4], dv[4];
    bool vld[4];
#pragma unroll
    for (int r = 0; r < 4; r++) {
        int row = rowbase + r;
        vld[r] = row < N;
        qv[r] = (HAS_AFF && vld[r]) ? q[row] : 0.f;
        dv[r] = (OM == 0 && vld[r]) ? dinv[row] : 0.f;
    }
    float sa[4], sq[4];
#pragma unroll
    for (int c = 0; c < 4; c++) { sa[c] = 0.f; sq[c] = 0.f; }

#pragma unroll
    for (int c = 0; c < 4; c++) {
        int col = c * 16 + l15;
        float bcol = bias[col];
        float ucol = HAS_AFF ? u[col] : 0.f;
        float Acol = (OM == 2) ? s0[col] : 0.f;
        float Ccol = (OM == 2) ? s1[col] : 0.f;
#pragma unroll
        for (int r = 0; r < 4; r++) {
            if (!vld[r]) continue;
            float o = acc[c][r] + bcol;
            if (HAS_AFF) o = fmaf(qv[r], ucol, o);
            float a = (MODE == 0) ? sigmoidf_(o)
                                  : ((MODE == 1) ? o : sigmoidf_(0.5f * o));
            int row = rowbase + r;
            if (OM == 0) {
                outh[(size_t)row * os + col] = f2h(a * dv[r]);
            } else if (OM == 1) {
                sa[c] += a;
                sq[c] += a * a;
            } else {
                outf[((size_t)row << 6) + col] = fmaf(a, Acol, Ccol);
            }
        }
    }

    if (OM == 1) {
        __shared__ float red[2][4][4][16];
#pragma unroll
        for (int c = 0; c < 4; c++) {
            sa[c] += __shfl_xor(sa[c], 16);
            sa[c] += __shfl_xor(sa[c], 32);
            sq[c] += __shfl_xor(sq[c], 16);
            sq[c] += __shfl_xor(sq[c], 32);
        }
        if (lg == 0) {
#pragma unroll
            for (int c = 0; c < 4; c++) {
                red[0][wv][c][l15] = sa[c];
                red[1][wv][c][l15] = sq[c];
            }
        }
        __syncthreads();
        if (wv == 0) {
            int c = lane >> 4, l = lane & 15;
            float t0 = red[0][0][c][l] + red[0][1][c][l] + red[0][2][c][l] + red[0][3][c][l];
            float t1 = red[1][0][c][l] + red[1][1][c][l] + red[1][2][c][l] + red[1][3][c][l];
            atomicAdd(&s0[lane], t0);
            atomicAdd(&s1[lane], t1);
        }
    }
}

// fused att1+str1 GEMM: shared A-frags, two weight sets, interleaved output rows.
__global__ __launch_bounds__(256) void gemm_dual(const ushort* __restrict__ zh,
                                                 const ushort* __restrict__ wfA,
                                                 const ushort* __restrict__ wfS,
                                                 const float* __restrict__ bA,
                                                 const float* __restrict__ bS,
                                                 const float* __restrict__ uA,
                                                 const float* __restrict__ uS,
                                                 const float* __restrict__ q,
                                                 const float* __restrict__ dinv,
                                                 ushort* __restrict__ outAB, int N) {
    int tid = threadIdx.x;
    int lane = tid & 63;
    int wv = tid >> 6;
    int l15 = lane & 15;
    int lg = lane >> 4;
    int tb = blockIdx.x * 64;

    const ushort* zrow = zh + ((size_t)(tb + wv * 16 + l15) << 6) + (lg << 3);
    f16x8 a0 = *reinterpret_cast<const f16x8*>(zrow);
    f16x8 a1 = *reinterpret_cast<const f16x8*>(zrow + 32);

    const f16x8* wa = reinterpret_cast<const f16x8*>(wfA) + lane;
    const f16x8* wsp = reinterpret_cast<const f16x8*>(wfS) + lane;

    f32x4 accA[4], accS[4];
#pragma unroll
    for (int c = 0; c < 4; c++) {
        f32x4 t = {0.f, 0.f, 0.f, 0.f};
        t = __builtin_amdgcn_mfma_f32_16x16x32_f16(a0, wa[(0 * 4 + c) * 64], t, 0, 0, 0);
        t = __builtin_amdgcn_mfma_f32_16x16x32_f16(a1, wa[(1 * 4 + c) * 64], t, 0, 0, 0);
        accA[c] = t;
        f32x4 t2 = {0.f, 0.f, 0.f, 0.f};
        t2 = __builtin_amdgcn_mfma_f32_16x16x32_f16(a0, wsp[(0 * 4 + c) * 64], t2, 0, 0, 0);
        t2 = __builtin_amdgcn_mfma_f32_16x16x32_f16(a1, wsp[(1 * 4 + c) * 64], t2, 0, 0, 0);
        accS[c] = t2;
    }

    int rowbase = tb + wv * 16 + lg * 4;
    float qv[4], dv[4];
    bool vld[4];
#pragma unroll
    for (int r = 0; r < 4; r++) {
        int row = rowbase + r;
        vld[r] = row < N;
        qv[r] = vld[r] ? q[row] : 0.f;
        dv[r] = vld[r] ? dinv[row] : 0.f;
    }
#pragma unroll
    for (int c = 0; c < 4; c++) {
        int col = c * 16 + l15;
        float bcA = bA[col], ucA = uA[col];
        float bcS = bS[col], ucS = uS[col];
#pragma unroll
        for (int r = 0; r < 4; r++) {
            if (!vld[r]) continue;
            int row = rowbase + r;
            float oA = fmaf(qv[r], ucA, accA[c][r] + bcA);
            float oS = fmaf(qv[r], ucS, accS[c][r] + bcS);
            float aA = sigmoidf_(oA);
            float aS = sigmoidf_(oS);
            outAB[((size_t)row << 7) + col] = f2h(aA * dv[r]);
            outAB[((size_t)row << 7) + 64 + col] = f2h(aS * dv[r]);
        }
    }
}

__global__ __launch_bounds__(256) void bn_apply_h(const ushort* __restrict__ actd,
                                                  const float* __restrict__ rdinv,
                                                  const float* __restrict__ A,
                                                  const float* __restrict__ C,
                                                  float* __restrict__ out, int N16) {
    int p = blockIdx.x * 256 + threadIdx.x;
    if (p >= N16) return;
    int n = p >> 4;
    int cb = (p & 15) * 4;
    float r = rdinv[n];
    ushort4 v = reinterpret_cast<const ushort4*>(actd)[p];
    float4 o;
    o.x = fmaf(h2f(v.x) * r, A[cb + 0], C[cb + 0]);
    o.y = fmaf(h2f(v.y) * r, A[cb + 1], C[cb + 1]);
    o.z = fmaf(h2f(v.z) * r, A[cb + 2], C[cb + 2]);
    o.w = fmaf(h2f(v.w) * r, A[cb + 3], C[cb + 3]);
    reinterpret_cast<float4*>(out)[p] = o;
}

// ---------------- launch ----------------

extern "C" void kernel_launch(void* const* d_in, const int* in_sizes, int n_in,
                              void* d_out, int out_size, void* d_ws, size_t ws_size,
                              hipStream_t stream) {
    const int N = in_sizes[0] / D;
    const int E = in_sizes[1] / 2;

    const float* x = (const float*)d_in[0];
    const int* ei = (const int*)d_in[1];
    const int* src_in = ei;
    const int* dst_in = ei + E;
    const float* encW = (const float*)d_in[3];
    const float* encb = (const float*)d_in[4];
    const float* encg = (const float*)d_in[5];
    const float* encbe = (const float*)d_in[6];
    const float* attW = (const float*)d_in[7];
    const float* attb = (const float*)d_in[8];
    const float* attg = (const float*)d_in[9];
    const float* attbe = (const float*)d_in[10];
    const float* strW = (const float*)d_in[11];
    const float* strb = (const float*)d_in[12];
    const float* strg = (const float*)d_in[13];
    const float* strbe = (const float*)d_in[14];

    const int NB = (N + 1023) >> 10;
    int CAP = (E + NB - 1) / NB;
    CAP = CAP + CAP / 8 + 256;
    CAP = (CAP + 255) & ~255;

    char* ws = (char*)d_ws;
    size_t off = 0;
    auto alloc = [&](size_t bytes) -> char* {
        char* p = ws + off;
        off += (bytes + 255) & ~(size_t)255;
        return p;
    };
    int* csr = (int*)alloc((size_t)(N + 1) * 4);
    int* bcur = (int*)alloc(128 * 4);
    int* boff = (int*)alloc(128 * 4);
    float* dinv = (float*)alloc((size_t)N * 4);
    float* rdinv = (float*)alloc((size_t)N * 4);
    float* q = (float*)alloc((size_t)N * 4);
    float* stats = (float*)alloc(6 * 128 * 4);
    float* aff = (float*)alloc(6 * 128 * 4);
    float* ubuf = (float*)alloc(6 * 64 * 4);
    ushort* wf = (ushort*)alloc(6 * 4096 * 2);
    int* sorted = (int*)alloc((size_t)E * 4);
    ushort* zh = (ushort*)alloc((size_t)(N + 64) * 64 * 2);
    size_t binbytes = (size_t)NB * CAP * 4;
    size_t zabbytes = (size_t)(N + 64) * 128 * 2;
    char* region = alloc(binbytes > zabbytes ? binbytes : zabbytes);
    uint* bins = (uint*)region;
    ushort* zab = (ushort*)region;
    ushort* hA = (ushort*)alloc((size_t)N * 64 * 2);
    ushort* hB = (ushort*)alloc((size_t)N * 64 * 2);
    ushort* hAB = (ushort*)alloc((size_t)(N + 64) * 128 * 2);

    float* out_str = (float*)d_out;
    float* out_att = out_str + (size_t)N * D;
    float* out_enc = out_att + (size_t)N * D;

    hipMemsetAsync(bcur, 0, 128 * 4, stream);
    hipMemsetAsync(stats, 0, 6 * 128 * 4, stream);

    int N16 = N * 16;
    int g16 = (N16 + 255) / 256;
    int gT = (N + 63) / 64;
    float invN = 1.0f / (float)N;

    float* A0 = aff + 0 * 128; float* C0 = A0 + 64;
    float* A1 = aff + 1 * 128; float* C1 = A1 + 64;
    float* A2 = aff + 2 * 128; float* C2 = A2 + 64;
    float* A3 = aff + 3 * 128; float* C3 = A3 + 64;
    float* A4 = aff + 4 * 128; float* C4 = A4 + 64;
    float* A5 = aff + 5 * 128; float* C5 = A5 + 64;
    ushort* wf0 = wf + 0 * 4096;
    ushort* wf1 = wf + 1 * 4096;
    ushort* wf2 = wf + 2 * 4096;
    ushort* wf3 = wf + 3 * 4096;
    ushort* wf4 = wf + 4 * 4096;
    ushort* wf5 = wf + 5 * 4096;

    // ---- CSR build ----
    bin_edges<<<(E + BCH - 1) / BCH, 256, 0, stream>>>(src_in, dst_in, bcur,
                                                       bins, CAP, E);
    scan_nb<<<1, 128, 0, stream>>>(bcur, boff, csr, NB, N, E);
    build_csr<<<NB, 256, 0, stream>>>(bins, bcur, boff, csr, sorted,
                                      dinv, rdinv, CAP, N);

    // ---- encoder layer 1 (q fused into first gather) ----
    prep_xd<<<g16, 256, 0, stream>>>(x, dinv, hA, N16);
    wprep<<<16, 256, 0, stream>>>(encW, wf0);
    agg_g<<<2048, 256, 0, stream>>>(hA, csr, sorted, dinv, rdinv, zh,
                                    nullptr, nullptr, q, N, E);
    gemm_mfma<0, false, 0><<<gT, 256, 0, stream>>>(zh, 64, wf0, encb, nullptr,
                                                   q, dinv, hB, 64, nullptr,
                                                   nullptr, nullptr, N);
    // ---- encoder layer 2 ----
    agg_g<<<2048, 256, 0, stream>>>(hB, csr, sorted, dinv, rdinv, zh,
                                    stats + 0, stats + 64, nullptr, N, E);
    layer_prep<<<1, 256, 0, stream>>>(stats + 0, stats + 64, encg, encbe,
                                      encW + 4096, A0, C0, ubuf + 0, wf1, invN);
    gemm_mfma<0, true, 0><<<gT, 256, 0, stream>>>(zh, 64, wf1, encb + 64, ubuf + 0,
                                                  q, dinv, hA, 64, nullptr,
                                                  nullptr, nullptr, N);
    // ---- z2 = Agg(x_enc act); enc2 stats ----
    agg_g<<<2048, 256, 0, stream>>>(hA, csr, sorted, dinv, rdinv, zh,
                                    stats + 128, stats + 192, nullptr, N, E);
    layer_prep<<<1, 256, 0, stream>>>(stats + 128, stats + 192, encg + 64,
                                      encbe + 64, attW, A1, C1, ubuf + 64, wf2, invN);
    layer_prep<<<1, 256, 0, stream>>>(stats + 128, stats + 192, encg + 64,
                                      encbe + 64, strW, A1, C1, ubuf + 128, wf3, invN);
    bn_apply_h<<<g16, 256, 0, stream>>>(hA, rdinv, A1, C1, out_enc, N16);
    gemm_dual<<<gT, 256, 0, stream>>>(zh, wf2, wf3, attb, strb, ubuf + 64,
                                      ubuf + 128, q, dinv, hAB, N);
    // ---- fused att1|str1 gather (+ both stats) ----
    agg_dual<<<2048, 256, 0, stream>>>(hAB, csr, sorted, dinv, rdinv, zab,
                                       stats + 256, stats + 320,
                                       stats + 512, stats + 576, N, E);
    // ---- attribute layer 2 (stats GEMM -> finalize -> apply GEMM) ----
    layer_prep<<<1, 256, 0, stream>>>(stats + 256, stats + 320, attg, attbe,
                                      attW + 4096, A2, C2, ubuf + 192, wf4, invN);
    gemm_mfma<1, true, 1><<<gT, 256, 0, stream>>>(zab, 128, wf4, attb + 64,
                                                  ubuf + 192, q, dinv, nullptr, 0,
                                                  nullptr, stats + 384, stats + 448, N);
    finalize_aff<<<1, 64, 0, stream>>>(stats + 384, stats + 448, attg + 64,
                                       attbe + 64, A3, C3, invN);
    gemm_mfma<1, true, 2><<<gT, 256, 0, stream>>>(zab, 128, wf4, attb + 64,
                                                  ubuf + 192, q, dinv, nullptr, 0,
                                                  out_att, A3, C3, N);
    // ---- structure layer 2 ----
    layer_prep<<<1, 256, 0, stream>>>(stats + 512, stats + 576, strg, strbe,
                                      strW + 4096, A4, C4, ubuf + 320, wf5, invN);
    gemm_mfma<2, true, 1><<<gT, 256, 0, stream>>>(zab + 64, 128, wf5, strb + 64,
                                                  ubuf + 320, q, dinv, nullptr, 0,
                                                  nullptr, stats + 640, stats + 704, N);
    finalize_aff<<<1, 64, 0, stream>>>(stats + 640, stats + 704, strg + 64,
                                       strbe + 64, A5, C5, invN);
    gemm_mfma<2, true, 2><<<gT, 256, 0, stream>>>(zab + 64, 128, wf5, strb + 64,
                                                  ubuf + 320, q, dinv, nullptr, 0,
                                                  out_str, A5, C5, N);
}